// Round 4
// baseline (352.671 us; speedup 1.0000x reference)
//
#include <hip/hip_runtime.h>

typedef unsigned int uint;
typedef unsigned short ushort;
typedef __bf16 v8bf __attribute__((ext_vector_type(8)));
typedef float v4f __attribute__((ext_vector_type(4)));
typedef float f2 __attribute__((ext_vector_type(2)));

#define CCH 256
#define HH 336
#define WW 336
#define HWSZ (HH*WW)
#define NROI 2000
#define KDIM 12544       // 49*256
#define MPAD 2048
#define SPLITK 14
#define KSP (KDIM/SPLITK)   // 896

__device__ __forceinline__ ushort bf16r(float f) {
  uint u = __float_as_uint(f);
  u += 0x7fffu + ((u >> 16) & 1u);   // RTNE
  return (ushort)(u >> 16);
}
__device__ __forceinline__ uint packbf(float a, float b) {
  return (uint)bf16r(a) | ((uint)bf16r(b) << 16);
}

typedef const __attribute__((address_space(1))) uint* gas_t;
typedef __attribute__((address_space(3))) uint* las_t;
__device__ __forceinline__ void async16(const void* g, void* l) {
  __builtin_amdgcn_global_load_lds((gas_t)g, (las_t)l, 16, 0, 0);
}

// features [256][336][336] fp32 -> ft [hw][c] bf16.
// v4: 128hw x 256ch tile; phase-1 float4/lane = 1KB/wave coalesced reads
// (was 256B/wave). LDS 128x134x4 = 68.6KB -> 2 blocks/CU. Phase-1 LDS b32
// writes are 8-way aliased but hide under the global-read pacing.
__global__ __launch_bounds__(256) void k_transpose(const float* __restrict__ f,
                                                   uint* __restrict__ ftu) {
  __shared__ uint T[128 * 134];
  int tid = threadIdx.x;
  int hw0 = blockIdx.x * 128;
  int hwq = tid & 31;             // hw-quad: hw = hw0 + hwq*4 .. +3
  int cp = tid >> 5;              // 0..7
#pragma unroll 2
  for (int j = 0; j < 16; ++j) {
    int cpair = j * 8 + cp;       // 0..127
    int c = cpair * 2;
    float4 fa = *(const float4*)&f[(size_t)c * HWSZ + hw0 + hwq * 4];
    float4 fb = *(const float4*)&f[(size_t)(c + 1) * HWSZ + hw0 + hwq * 4];
    T[(hwq * 4 + 0) * 134 + cpair] = packbf(fa.x, fb.x);
    T[(hwq * 4 + 1) * 134 + cpair] = packbf(fa.y, fb.y);
    T[(hwq * 4 + 2) * 134 + cpair] = packbf(fa.z, fb.z);
    T[(hwq * 4 + 3) * 134 + cpair] = packbf(fa.w, fb.w);
  }
  __syncthreads();
  int co = tid & 31, r = tid >> 5;   // 8 rows per iter
#pragma unroll 4
  for (int i = 0; i < 16; ++i) {
    int row = i * 8 + r;
    uint2 v0 = *(const uint2*)&T[row * 134 + co * 4];
    uint2 v1 = *(const uint2*)&T[row * 134 + co * 4 + 2];
    *(uint4*)(ftu + (size_t)(hw0 + row) * 128 + co * 4) =
        make_uint4(v0.x, v0.y, v1.x, v1.y);
  }
}

// Fused preprocessing: blocks 0..391 = w1perm, 392..423 = w2t, 424 = sort.
__global__ __launch_bounds__(256) void k_prep(const float* __restrict__ w1,
                                              uint* __restrict__ w1t_u,
                                              const float* __restrict__ w2,
                                              ushort* __restrict__ w2t,
                                              const int* __restrict__ rois,
                                              int* __restrict__ perm) {
  __shared__ ushort T[32][258];
  __shared__ int hist[64];
  __shared__ int keys[NROI];
  int tid = threadIdx.x;
  int b = blockIdx.x;
  if (b < 392) {
    // w1 [12544][256] fp32 (k=c*49+bin) -> w1t bf16 [n][k'], k'=bin*256+c
    int bin = b % 49;
    int c0 = (b / 49) * 32;
    int n = tid;
    for (int i = 0; i < 32; ++i)
      T[i][n] = bf16r(w1[(size_t)((c0 + i) * 49 + bin) * 256 + n]);
    __syncthreads();
    int cc = tid & 15;
    int nb = tid >> 4;
    for (int rep = 0; rep < 16; ++rep) {
      int nn = rep * 16 + nb;
      uint v = (uint)T[2 * cc][nn] | ((uint)T[2 * cc + 1][nn] << 16);
      w1t_u[(size_t)nn * (KDIM / 2) + bin * 128 + c0 / 2 + cc] = v;
    }
  } else if (b < 424) {
    // w2 [256][256] -> w2t bf16 [n][k]
    int n = (b - 392) * 8 + (tid >> 5);
    for (int kl = 0; kl < 8; ++kl) {
      int k = kl * 32 + (tid & 31);
      w2t[n * 256 + k] = bf16r(w2[k * 256 + n]);
    }
  } else {
    // counting-sort ROIs by spatial tile (8x8 grid of 42px) -> perm
    if (tid < 64) hist[tid] = 0;
    __syncthreads();
    for (int i = tid; i < NROI; i += 256) {
      int x1 = rois[i * 4 + 0], y1 = rois[i * 4 + 1];
      int x2 = rois[i * 4 + 2], y2 = rois[i * 4 + 3];
      int cx = (x1 + x2) >> 1, cy = (y1 + y2) >> 1;
      int k = (cy / 42) * 8 + (cx / 42);
      keys[i] = k;
      atomicAdd(&hist[k], 1);
    }
    __syncthreads();
    if (tid < 64) {               // wave-0 exclusive prefix scan
      int v = hist[tid];
      int s = v;
#pragma unroll
      for (int d = 1; d < 64; d <<= 1) {
        int t2 = __shfl_up(s, d, 64);
        if (tid >= d) s += t2;
      }
      hist[tid] = s - v;
    }
    __syncthreads();
    for (int i = tid; i < NROI; i += 256) {
      int pos = atomicAdd(&hist[keys[i]], 1);
      perm[pos] = i;
    }
  }
}

// Round-4: lane = channel-quad, whole wave = one pixel (64 lanes x uint2 =
// all 256 ch, 512B coalesced). Mapping = round-0 measured best: grid 14000
// x 64thr, L -> XCD=L&7, i=L>>3, slot=XCD*250+i/7, by=i%7.
// Why: previous par-split made x-loops lane-divergent (both halves' trip
// counts issue under exec masks) and forced an 8x shfl_xor DS epilogue per
// bin. Derived from counters: ~3.4k VALU instrs/wave issued vs ~1.2k useful.
// Now all loops are wave-uniform and each lane owns its 4 channels
// end-to-end: epilogue = merge + scale + 2 packbf + uint2 store, no
// shuffles. 2x2 (row-pair x col-pair) unroll keeps 4 independent loads in
// flight. Output layout in rf is byte-identical to round-3.
__device__ __forceinline__ void pkacc(f2& acc, uint u) {
  f2 t;
  t.x = __uint_as_float(u << 16);
  t.y = __uint_as_float(u & 0xffff0000u);
  asm("v_pk_add_f32 %0, %1, %0" : "+v"(acc) : "v"(t));
}
__device__ __forceinline__ void pkadd(f2& acc, f2 v) {
  asm("v_pk_add_f32 %0, %1, %0" : "+v"(acc) : "v"(v));
}
// accumulate uint2 (4 channels) into S[2]
#define UNPK2(S, u) do { pkacc(S[0], (u).x); pkacc(S[1], (u).y); } while (0)

__global__ __launch_bounds__(64) void k_pool(const int* __restrict__ rois,
                                             const int* __restrict__ perm,
                                             const uint* __restrict__ ftu,
                                             uint2* __restrict__ rfu2) {
  int L = blockIdx.x;
  int i = L >> 3;
  int slot = (L & 7) * 250 + i / 7;
  int by = i % 7;
  int n = perm[slot];
  int lane = threadIdx.x;            // channel-quad 0..63
  int x1 = rois[n * 4 + 0], y1 = rois[n * 4 + 1];
  int x2 = rois[n * 4 + 2], y2 = rois[n * 4 + 3];
  int Lw = x2 - x1 + 1, Lh = y2 - y1 + 1;
  int ylo = y1 + (by * Lh) / 7;
  int yhi = y1 + ((by + 1) * Lh + 6) / 7;
  int rh = yhi - ylo;
  uint ob = ((uint)n * 49 + (uint)by * 7) * 64 + lane;   // uint2 units
  for (int b = 0; b < 7; ++b) {
    int lo = x1 + (b * Lw) / 7;
    int hi = x1 + ((b + 1) * Lw + 6) / 7;
    f2 A[2], B[2], C[2], D[2];
#pragma unroll
    for (int j = 0; j < 2; ++j) {
      A[j] = (f2){0.f, 0.f}; B[j] = (f2){0.f, 0.f};
      C[j] = (f2){0.f, 0.f}; D[j] = (f2){0.f, 0.f};
    }
    int y = ylo;
    for (; y + 1 < yhi; y += 2) {           // row pair, wave-uniform
      const uint2* p = (const uint2*)(ftu + (size_t)(y * WW + lo) * 128) + lane;
      const uint2* q = p + 336 * 64;        // next row (uint2 stride 64/px)
      int x = lo;
      for (; x + 1 < hi; x += 2) {          // col pair
        uint2 u0 = p[0], u1 = p[64];
        uint2 v0 = q[0], v1 = q[64];
        p += 128; q += 128;
        UNPK2(A, u0);
        UNPK2(B, u1);
        UNPK2(C, v0);
        UNPK2(D, v1);
      }
      if (x < hi) {                         // odd col
        uint2 u0 = p[0], v0 = q[0];
        UNPK2(A, u0);
        UNPK2(C, v0);
      }
    }
    if (y < yhi) {                          // odd tail row
      const uint2* p = (const uint2*)(ftu + (size_t)(y * WW + lo) * 128) + lane;
      int x = lo;
      for (; x + 1 < hi; x += 2) {
        uint2 u0 = p[0], u1 = p[64];
        p += 128;
        UNPK2(A, u0);
        UNPK2(B, u1);
      }
      if (x < hi) {
        uint2 u0 = p[0];
        UNPK2(A, u0);
      }
    }
#pragma unroll
    for (int j = 0; j < 2; ++j) {
      pkadd(A[j], B[j]);
      pkadd(C[j], D[j]);
      pkadd(A[j], C[j]);
    }
    float inv = 1.0f / (float)(rh * (hi - lo));
    uint2 o;
    o.x = packbf(A[0].x * inv, A[0].y * inv);
    o.y = packbf(A[1].x * inv, A[1].y * inv);
    rfu2[ob + b * 64] = o;
  }
}

// NT GEMM: A=rf [2048][12544], B=w1t [256][12544], 64x128 tiles, split-K.
__global__ __launch_bounds__(256) void k_gemm1(const ushort* __restrict__ A,
                                               const ushort* __restrict__ B,
                                               float* __restrict__ P) {
  __shared__ ushort As[64 * 64];
  __shared__ ushort Bs[128 * 64];
  int m0 = blockIdx.x * 64;
  int n0 = blockIdx.y * 128;
  int ks = blockIdx.z;
  int k0 = ks * KSP;
  int tid = threadIdx.x;
  int lane = tid & 63, wv = tid >> 6;
  int wm = wv & 1, wn = wv >> 1;
  int lm = lane & 15, quad = lane >> 4;
  int srow = tid >> 3, scol = (tid & 7) * 8;
  v4f acc[2][4];
#pragma unroll
  for (int i = 0; i < 2; ++i)
#pragma unroll
    for (int j = 0; j < 4; ++j) acc[i][j] = (v4f){0.f, 0.f, 0.f, 0.f};
  const ushort* Ab = A + (size_t)(m0 + srow) * KDIM + k0 + scol;
  const ushort* Bb = B + (size_t)(n0 + srow) * KDIM + k0 + scol;
  for (int kt = 0; kt < KSP / 64; ++kt) {
    __syncthreads();
#pragma unroll
    for (int r = 0; r < 2; ++r)
      async16(Ab + (size_t)(r * 32) * KDIM + kt * 64, &As[(srow + r * 32) * 64 + scol]);
#pragma unroll
    for (int r = 0; r < 4; ++r)
      async16(Bb + (size_t)(r * 32) * KDIM + kt * 64, &Bs[(srow + r * 32) * 64 + scol]);
    __syncthreads();
#pragma unroll
    for (int kk = 0; kk < 64; kk += 32) {
      v8bf a[2], b[4];
#pragma unroll
      for (int i = 0; i < 2; ++i)
        a[i] = *(const v8bf*)&As[(wm * 32 + i * 16 + lm) * 64 + kk + quad * 8];
#pragma unroll
      for (int j = 0; j < 4; ++j)
        b[j] = *(const v8bf*)&Bs[(wn * 64 + j * 16 + lm) * 64 + kk + quad * 8];
#pragma unroll
      for (int i = 0; i < 2; ++i)
#pragma unroll
        for (int j = 0; j < 4; ++j)
          acc[i][j] = __builtin_amdgcn_mfma_f32_16x16x32_bf16(a[i], b[j], acc[i][j], 0, 0, 0);
    }
  }
  float* Pb = P + (size_t)ks * MPAD * 256;
#pragma unroll
  for (int i = 0; i < 2; ++i)
#pragma unroll
    for (int j = 0; j < 4; ++j) {
      int row = m0 + wm * 32 + i * 16 + quad * 4;
      int col = n0 + wn * 64 + j * 16 + lm;
#pragma unroll
      for (int r = 0; r < 4; ++r)
        Pb[(size_t)(row + r) * 256 + col] = acc[i][j][r];
    }
}

// sum split-K partials + bias + relu -> h1 bf16 [2048][256]
__global__ __launch_bounds__(256) void k_reduce(const float* __restrict__ P,
                                                const float* __restrict__ b1,
                                                uint* __restrict__ h1u) {
  int idx = blockIdx.x * 256 + threadIdx.x;  // < 2048*128
  int m = idx >> 7, np = idx & 127;
  const float2* Pp = (const float2*)P;
  float2 s = {0.f, 0.f};
#pragma unroll
  for (int ks = 0; ks < SPLITK; ++ks) {
    float2 v = Pp[(size_t)(ks * MPAD + m) * 128 + np];
    s.x += v.x; s.y += v.y;
  }
  s.x += b1[2 * np]; s.y += b1[2 * np + 1];
  s.x = fmaxf(s.x, 0.f); s.y = fmaxf(s.y, 0.f);
  h1u[idx] = packbf(s.x, s.y);
}

// GEMM2 (64 rows x full N=256, K=256) + fused cls/reg heads
__global__ __launch_bounds__(256) void k_gemm2(const ushort* __restrict__ h1b,
                                               const ushort* __restrict__ w2t,
                                               const float* __restrict__ b2,
                                               const float* __restrict__ wcls,
                                               const float* __restrict__ bcls,
                                               const float* __restrict__ wreg,
                                               const float* __restrict__ breg,
                                               float* __restrict__ out) {
  __shared__ ushort As2[64 * 64];
  __shared__ ushort Bs2[256 * 64];
  __shared__ float Hs[64 * 257];
  int tid = threadIdx.x;
  int r0 = blockIdx.x * 64;
  int lane = tid & 63, wv = tid >> 6;
  int lm = lane & 15, quad = lane >> 4;
  int srow = tid >> 3, scol = (tid & 7) * 8;
  v4f acc[16];
#pragma unroll
  for (int j = 0; j < 16; ++j) acc[j] = (v4f){0.f, 0.f, 0.f, 0.f};
  for (int kt = 0; kt < 4; ++kt) {
    __syncthreads();
#pragma unroll
    for (int r = 0; r < 2; ++r)
      async16(h1b + (size_t)(r0 + srow + r * 32) * 256 + kt * 64 + scol,
              &As2[(srow + r * 32) * 64 + scol]);
#pragma unroll
    for (int r = 0; r < 8; ++r)
      async16(w2t + (size_t)(srow + r * 32) * 256 + kt * 64 + scol,
              &Bs2[(srow + r * 32) * 64 + scol]);
    __syncthreads();
#pragma unroll
    for (int kk = 0; kk < 64; kk += 32) {
      v8bf a = *(const v8bf*)&As2[(wv * 16 + lm) * 64 + kk + quad * 8];
#pragma unroll
      for (int j = 0; j < 16; ++j) {
        v8bf b = *(const v8bf*)&Bs2[(j * 16 + lm) * 64 + kk + quad * 8];
        acc[j] = __builtin_amdgcn_mfma_f32_16x16x32_bf16(a, b, acc[j], 0, 0, 0);
      }
    }
  }
#pragma unroll
  for (int j = 0; j < 16; ++j) {
    int nn = j * 16 + lm;
    float bb = b2[nn];
#pragma unroll
    for (int r = 0; r < 4; ++r) {
      int row = wv * 16 + quad * 4 + r;
      Hs[row * 257 + nn] = fmaxf(acc[j][r] + bb, 0.f);
    }
  }
  __syncthreads();
  for (int o = tid; o < 384; o += 256) {
    int hd = o >> 6, r = o & 63;
    int grow = r0 + r;
    float d = 0.f;
    if (hd < 2) {
      for (int k = 0; k < 256; ++k) d += Hs[r * 257 + k] * wcls[k * 2 + hd];
      d += bcls[hd];
      if (grow < NROI) out[grow * 2 + hd] = d;
    } else {
      int h4 = hd - 2;
      for (int k = 0; k < 256; ++k) d += Hs[r * 257 + k] * wreg[k * 4 + h4];
      d += breg[h4];
      if (grow < NROI) out[4000 + grow * 4 + h4] = d;
    }
  }
}

extern "C" void kernel_launch(void* const* d_in, const int* in_sizes, int n_in,
                              void* d_out, int out_size, void* d_ws, size_t ws_size,
                              hipStream_t stream) {
  const float* features = (const float*)d_in[0];
  const int* rois = (const int*)d_in[1];
  const float* w1 = (const float*)d_in[2];
  const float* b1 = (const float*)d_in[3];
  const float* w2 = (const float*)d_in[4];
  const float* b2 = (const float*)d_in[5];
  const float* wcls = (const float*)d_in[6];
  const float* bcls = (const float*)d_in[7];
  const float* wreg = (const float*)d_in[8];
  const float* breg = (const float*)d_in[9];
  char* ws = (char*)d_ws;
  ushort* ft  = (ushort*)(ws + 0);          // 57,802,752 B
  ushort* w1t = (ushort*)(ws + 57802752);   //  6,422,528 B
  ushort* w2t = (ushort*)(ws + 64225280);   //    131,072 B
  ushort* rf  = (ushort*)(ws + 64356352);   // 51,380,224 B (2048 rows; rows
                                            // 2000+ are GEMM padding)
  // perm lives in rf's padding rows (read by gemm1 as harmless tiny bf16)
  int*    perm = (int*)(ws + 64356352 + (size_t)NROI * KDIM * 2);
  float*  P   = (float*)(ws + 115736576);   // 29,360,128 B
  ushort* h1b = (ushort*)(ws + 145096704);  //  1,048,576 B
  float* out = (float*)d_out;

  hipLaunchKernelGGL(k_transpose, dim3(HWSZ / 128), dim3(256), 0, stream,
                     features, (uint*)ft);
  hipLaunchKernelGGL(k_prep, dim3(425), dim3(256), 0, stream,
                     w1, (uint*)w1t, w2, w2t, rois, perm);
  hipLaunchKernelGGL(k_pool, dim3(NROI * 7), dim3(64), 0, stream, rois, perm,
                     (const uint*)ft, (uint2*)rf);
  hipLaunchKernelGGL(k_gemm1, dim3(32, 2, SPLITK), dim3(256), 0, stream, rf, w1t, P);
  hipLaunchKernelGGL(k_reduce, dim3(1024), dim3(256), 0, stream, P, b1, (uint*)h1b);
  hipLaunchKernelGGL(k_gemm2, dim3(32), dim3(256), 0, stream, h1b, w2t, b2, wcls, bcls, wreg, breg, out);
}

// Round 5
// 341.567 us; speedup vs baseline: 1.0325x; 1.0325x over previous
//
#include <hip/hip_runtime.h>

typedef unsigned int uint;
typedef unsigned short ushort;
typedef __bf16 v8bf __attribute__((ext_vector_type(8)));
typedef float v4f __attribute__((ext_vector_type(4)));
typedef float f2 __attribute__((ext_vector_type(2)));

#define CCH 256
#define HH 336
#define WW 336
#define HWSZ (HH*WW)
#define NROI 2000
#define KDIM 12544       // 49*256
#define MPAD 2048
#define SPLITK 14
#define KSP (KDIM/SPLITK)   // 896

__device__ __forceinline__ ushort bf16r(float f) {
  uint u = __float_as_uint(f);
  u += 0x7fffu + ((u >> 16) & 1u);   // RTNE
  return (ushort)(u >> 16);
}
__device__ __forceinline__ uint packbf(float a, float b) {
  return (uint)bf16r(a) | ((uint)bf16r(b) << 16);
}

typedef const __attribute__((address_space(1))) uint* gas_t;
typedef __attribute__((address_space(3))) uint* las_t;
__device__ __forceinline__ void async16(const void* g, void* l) {
  __builtin_amdgcn_global_load_lds((gas_t)g, (las_t)l, 16, 0, 0);
}

// features [256][336][336] fp32 -> ft [hw][c] bf16.
// v4: 128hw x 256ch tile; phase-1 float4/lane = 1KB/wave coalesced reads
// (was 256B/wave). LDS 128x134x4 = 68.6KB -> 2 blocks/CU. Phase-1 LDS b32
// writes are 8-way aliased but hide under the global-read pacing.
__global__ __launch_bounds__(256) void k_transpose(const float* __restrict__ f,
                                                   uint* __restrict__ ftu) {
  __shared__ uint T[128 * 134];
  int tid = threadIdx.x;
  int hw0 = blockIdx.x * 128;
  int hwq = tid & 31;             // hw-quad: hw = hw0 + hwq*4 .. +3
  int cp = tid >> 5;              // 0..7
#pragma unroll 2
  for (int j = 0; j < 16; ++j) {
    int cpair = j * 8 + cp;       // 0..127
    int c = cpair * 2;
    float4 fa = *(const float4*)&f[(size_t)c * HWSZ + hw0 + hwq * 4];
    float4 fb = *(const float4*)&f[(size_t)(c + 1) * HWSZ + hw0 + hwq * 4];
    T[(hwq * 4 + 0) * 134 + cpair] = packbf(fa.x, fb.x);
    T[(hwq * 4 + 1) * 134 + cpair] = packbf(fa.y, fb.y);
    T[(hwq * 4 + 2) * 134 + cpair] = packbf(fa.z, fb.z);
    T[(hwq * 4 + 3) * 134 + cpair] = packbf(fa.w, fb.w);
  }
  __syncthreads();
  int co = tid & 31, r = tid >> 5;   // 8 rows per iter
#pragma unroll 4
  for (int i = 0; i < 16; ++i) {
    int row = i * 8 + r;
    uint2 v0 = *(const uint2*)&T[row * 134 + co * 4];
    uint2 v1 = *(const uint2*)&T[row * 134 + co * 4 + 2];
    *(uint4*)(ftu + (size_t)(hw0 + row) * 128 + co * 4) =
        make_uint4(v0.x, v0.y, v1.x, v1.y);
  }
}

// Fused preprocessing: blocks 0..391 = w1perm, 392..423 = w2t, 424 = sort.
__global__ __launch_bounds__(256) void k_prep(const float* __restrict__ w1,
                                              uint* __restrict__ w1t_u,
                                              const float* __restrict__ w2,
                                              ushort* __restrict__ w2t,
                                              const int* __restrict__ rois,
                                              int* __restrict__ perm) {
  __shared__ ushort T[32][258];
  __shared__ int hist[64];
  __shared__ int keys[NROI];
  int tid = threadIdx.x;
  int b = blockIdx.x;
  if (b < 392) {
    // w1 [12544][256] fp32 (k=c*49+bin) -> w1t bf16 [n][k'], k'=bin*256+c
    int bin = b % 49;
    int c0 = (b / 49) * 32;
    int n = tid;
    for (int i = 0; i < 32; ++i)
      T[i][n] = bf16r(w1[(size_t)((c0 + i) * 49 + bin) * 256 + n]);
    __syncthreads();
    int cc = tid & 15;
    int nb = tid >> 4;
    for (int rep = 0; rep < 16; ++rep) {
      int nn = rep * 16 + nb;
      uint v = (uint)T[2 * cc][nn] | ((uint)T[2 * cc + 1][nn] << 16);
      w1t_u[(size_t)nn * (KDIM / 2) + bin * 128 + c0 / 2 + cc] = v;
    }
  } else if (b < 424) {
    // w2 [256][256] -> w2t bf16 [n][k]
    int n = (b - 392) * 8 + (tid >> 5);
    for (int kl = 0; kl < 8; ++kl) {
      int k = kl * 32 + (tid & 31);
      w2t[n * 256 + k] = bf16r(w2[k * 256 + n]);
    }
  } else {
    // counting-sort ROIs by spatial tile (8x8 grid of 42px) -> perm
    if (tid < 64) hist[tid] = 0;
    __syncthreads();
    for (int i = tid; i < NROI; i += 256) {
      int x1 = rois[i * 4 + 0], y1 = rois[i * 4 + 1];
      int x2 = rois[i * 4 + 2], y2 = rois[i * 4 + 3];
      int cx = (x1 + x2) >> 1, cy = (y1 + y2) >> 1;
      int k = (cy / 42) * 8 + (cx / 42);
      keys[i] = k;
      atomicAdd(&hist[k], 1);
    }
    __syncthreads();
    if (tid < 64) {               // wave-0 exclusive prefix scan
      int v = hist[tid];
      int s = v;
#pragma unroll
      for (int d = 1; d < 64; d <<= 1) {
        int t2 = __shfl_up(s, d, 64);
        if (tid >= d) s += t2;
      }
      hist[tid] = s - v;
    }
    __syncthreads();
    for (int i = tid; i < NROI; i += 256) {
      int pos = atomicAdd(&hist[keys[i]], 1);
      perm[pos] = i;
    }
  }
}

// Round-5: k_pool restructured for memory-level parallelism.
// Evidence (r0-r4): per-unit residency ~52k cycles for ~70 loads => loads
// near-serialized at L2-miss latency (FETCH 115MB >> ft 58MB). The per-bin
// loops average ~1.6 iters so the load pipeline never fills and drains at
// every bin edge. Fix:
//  (1) rh-templated body (rh in 1..7, wave-uniform switch): process ROI in
//      4-column chunks, issuing all 4*rh independent dwordx2 loads
//      (static row-pointers + imm offsets) BEFORE any accumulation ->
//      4..28 loads in flight.
//  (2) single x-walk with running prefix P; bin sum = P(hi_b)-P(lo_b) via
//      two snapshot regs (bins overlap <=1 col, so <=2 open at once;
//      equal-hi double-close handled by uniform while). Every pixel loaded
//      exactly once; no per-bin accumulator resets; all boundary logic SALU.
// Mapping/layout unchanged from round-4 (lane=channel-quad, wave=pixel-col,
// grid 14000x64, XCD-sorted slots; rf bytes identical).
__device__ __forceinline__ void pkacc(f2& acc, uint u) {
  f2 t;
  t.x = __uint_as_float(u << 16);
  t.y = __uint_as_float(u & 0xffff0000u);
  asm("v_pk_add_f32 %0, %1, %0" : "+v"(acc) : "v"(t));
}
// accumulate uint2 (4 channels) into S[2]
#define UNPK2(S, u) do { pkacc(S[0], (u).x); pkacc(S[1], (u).y); } while (0)

template <int RH>
__device__ __forceinline__ void pool_unit(const uint2* __restrict__ ftu2,
                                          uint2* __restrict__ rfu2,
                                          int x1, int Lw, int ylo, int lane,
                                          uint ob) {
  const uint2* pr[RH];
#pragma unroll
  for (int r = 0; r < RH; ++r)
    pr[r] = ftu2 + (size_t)((ylo + r) * WW + x1) * 64 + lane;
  int xend = x1 + Lw;
  // bin-walk state (all wave-uniform scalars)
  int b = 0;
  int lo_cur = x1;
  int hi_cur = x1 + (Lw + 6) / 7;     // hi_0 = x1 + ceil(Lw/7)
  int lo_next = x1 + Lw / 7;          // lo_1
  f2 P[2], Lc[2], Ln[2];
  P[0] = (f2){0.f, 0.f}; P[1] = (f2){0.f, 0.f};
  Lc[0] = (f2){0.f, 0.f}; Lc[1] = (f2){0.f, 0.f};
  Ln[0] = (f2){0.f, 0.f}; Ln[1] = (f2){0.f, 0.f};
  const float invr = 1.0f / (float)RH;
  for (int xc = x1; xc < xend; xc += 4) {
    uint2 v[4][RH];
#pragma unroll
    for (int c = 0; c < 4; ++c)
#pragma unroll
      for (int r = 0; r < RH; ++r)
        v[c][r] = pr[r][c * 64];       // imm offset c*512B; all independent
#pragma unroll
    for (int r = 0; r < RH; ++r) pr[r] += 256;   // advance 4 pixels
#pragma unroll
    for (int c = 0; c < 4; ++c) {
      int x = xc + c;
      if (x < xend) {
#pragma unroll
        for (int r = 0; r < RH; ++r) UNPK2(P, v[c][r]);
        int xp = x + 1;
        if (xp == lo_next) { Ln[0] = P[0]; Ln[1] = P[1]; }
        while (b < 7 && xp == hi_cur) {
          float inv = invr / (float)(hi_cur - lo_cur);
          uint2 o;
          o.x = packbf((P[0].x - Lc[0].x) * inv, (P[0].y - Lc[0].y) * inv);
          o.y = packbf((P[1].x - Lc[1].x) * inv, (P[1].y - Lc[1].y) * inv);
          rfu2[ob + b * 64] = o;
          ++b;
          Lc[0] = Ln[0]; Lc[1] = Ln[1];
          lo_cur = lo_next;
          hi_cur = x1 + ((b + 1) * Lw + 6) / 7;
          lo_next = x1 + ((b + 1) * Lw) / 7;
          if (xp == lo_next) { Ln[0] = P[0]; Ln[1] = P[1]; }
        }
      }
    }
  }
}

__global__ __launch_bounds__(64) void k_pool(const int* __restrict__ rois,
                                             const int* __restrict__ perm,
                                             const uint2* __restrict__ ftu2,
                                             uint2* __restrict__ rfu2) {
  int L = blockIdx.x;
  int i = L >> 3;
  int slot = (L & 7) * 250 + i / 7;
  int by = i % 7;
  int n = perm[slot];
  int lane = threadIdx.x;            // channel-quad 0..63
  int x1 = rois[n * 4 + 0], y1 = rois[n * 4 + 1];
  int x2 = rois[n * 4 + 2], y2 = rois[n * 4 + 3];
  int Lw = x2 - x1 + 1, Lh = y2 - y1 + 1;
  int ylo = y1 + (by * Lh) / 7;
  int yhi = y1 + ((by + 1) * Lh + 6) / 7;
  int rh = yhi - ylo;                // 1..7
  uint ob = ((uint)n * 49 + (uint)by * 7) * 64 + lane;
  switch (rh) {
    case 1: pool_unit<1>(ftu2, rfu2, x1, Lw, ylo, lane, ob); break;
    case 2: pool_unit<2>(ftu2, rfu2, x1, Lw, ylo, lane, ob); break;
    case 3: pool_unit<3>(ftu2, rfu2, x1, Lw, ylo, lane, ob); break;
    case 4: pool_unit<4>(ftu2, rfu2, x1, Lw, ylo, lane, ob); break;
    case 5: pool_unit<5>(ftu2, rfu2, x1, Lw, ylo, lane, ob); break;
    case 6: pool_unit<6>(ftu2, rfu2, x1, Lw, ylo, lane, ob); break;
    default: pool_unit<7>(ftu2, rfu2, x1, Lw, ylo, lane, ob); break;
  }
}

// NT GEMM: A=rf [2048][12544], B=w1t [256][12544], 64x128 tiles, split-K.
__global__ __launch_bounds__(256) void k_gemm1(const ushort* __restrict__ A,
                                               const ushort* __restrict__ B,
                                               float* __restrict__ P) {
  __shared__ ushort As[64 * 64];
  __shared__ ushort Bs[128 * 64];
  int m0 = blockIdx.x * 64;
  int n0 = blockIdx.y * 128;
  int ks = blockIdx.z;
  int k0 = ks * KSP;
  int tid = threadIdx.x;
  int lane = tid & 63, wv = tid >> 6;
  int wm = wv & 1, wn = wv >> 1;
  int lm = lane & 15, quad = lane >> 4;
  int srow = tid >> 3, scol = (tid & 7) * 8;
  v4f acc[2][4];
#pragma unroll
  for (int i = 0; i < 2; ++i)
#pragma unroll
    for (int j = 0; j < 4; ++j) acc[i][j] = (v4f){0.f, 0.f, 0.f, 0.f};
  const ushort* Ab = A + (size_t)(m0 + srow) * KDIM + k0 + scol;
  const ushort* Bb = B + (size_t)(n0 + srow) * KDIM + k0 + scol;
  for (int kt = 0; kt < KSP / 64; ++kt) {
    __syncthreads();
#pragma unroll
    for (int r = 0; r < 2; ++r)
      async16(Ab + (size_t)(r * 32) * KDIM + kt * 64, &As[(srow + r * 32) * 64 + scol]);
#pragma unroll
    for (int r = 0; r < 4; ++r)
      async16(Bb + (size_t)(r * 32) * KDIM + kt * 64, &Bs[(srow + r * 32) * 64 + scol]);
    __syncthreads();
#pragma unroll
    for (int kk = 0; kk < 64; kk += 32) {
      v8bf a[2], b[4];
#pragma unroll
      for (int i = 0; i < 2; ++i)
        a[i] = *(const v8bf*)&As[(wm * 32 + i * 16 + lm) * 64 + kk + quad * 8];
#pragma unroll
      for (int j = 0; j < 4; ++j)
        b[j] = *(const v8bf*)&Bs[(wn * 64 + j * 16 + lm) * 64 + kk + quad * 8];
#pragma unroll
      for (int i = 0; i < 2; ++i)
#pragma unroll
        for (int j = 0; j < 4; ++j)
          acc[i][j] = __builtin_amdgcn_mfma_f32_16x16x32_bf16(a[i], b[j], acc[i][j], 0, 0, 0);
    }
  }
  float* Pb = P + (size_t)ks * MPAD * 256;
#pragma unroll
  for (int i = 0; i < 2; ++i)
#pragma unroll
    for (int j = 0; j < 4; ++j) {
      int row = m0 + wm * 32 + i * 16 + quad * 4;
      int col = n0 + wn * 64 + j * 16 + lm;
#pragma unroll
      for (int r = 0; r < 4; ++r)
        Pb[(size_t)(row + r) * 256 + col] = acc[i][j][r];
    }
}

// sum split-K partials + bias + relu -> h1 bf16 [2048][256]
__global__ __launch_bounds__(256) void k_reduce(const float* __restrict__ P,
                                                const float* __restrict__ b1,
                                                uint* __restrict__ h1u) {
  int idx = blockIdx.x * 256 + threadIdx.x;  // < 2048*128
  int m = idx >> 7, np = idx & 127;
  const float2* Pp = (const float2*)P;
  float2 s = {0.f, 0.f};
#pragma unroll
  for (int ks = 0; ks < SPLITK; ++ks) {
    float2 v = Pp[(size_t)(ks * MPAD + m) * 128 + np];
    s.x += v.x; s.y += v.y;
  }
  s.x += b1[2 * np]; s.y += b1[2 * np + 1];
  s.x = fmaxf(s.x, 0.f); s.y = fmaxf(s.y, 0.f);
  h1u[idx] = packbf(s.x, s.y);
}

// GEMM2 (64 rows x full N=256, K=256) + fused cls/reg heads
__global__ __launch_bounds__(256) void k_gemm2(const ushort* __restrict__ h1b,
                                               const ushort* __restrict__ w2t,
                                               const float* __restrict__ b2,
                                               const float* __restrict__ wcls,
                                               const float* __restrict__ bcls,
                                               const float* __restrict__ wreg,
                                               const float* __restrict__ breg,
                                               float* __restrict__ out) {
  __shared__ ushort As2[64 * 64];
  __shared__ ushort Bs2[256 * 64];
  __shared__ float Hs[64 * 257];
  int tid = threadIdx.x;
  int r0 = blockIdx.x * 64;
  int lane = tid & 63, wv = tid >> 6;
  int lm = lane & 15, quad = lane >> 4;
  int srow = tid >> 3, scol = (tid & 7) * 8;
  v4f acc[16];
#pragma unroll
  for (int j = 0; j < 16; ++j) acc[j] = (v4f){0.f, 0.f, 0.f, 0.f};
  for (int kt = 0; kt < 4; ++kt) {
    __syncthreads();
#pragma unroll
    for (int r = 0; r < 2; ++r)
      async16(h1b + (size_t)(r0 + srow + r * 32) * 256 + kt * 64 + scol,
              &As2[(srow + r * 32) * 64 + scol]);
#pragma unroll
    for (int r = 0; r < 8; ++r)
      async16(w2t + (size_t)(srow + r * 32) * 256 + kt * 64 + scol,
              &Bs2[(srow + r * 32) * 64 + scol]);
    __syncthreads();
#pragma unroll
    for (int kk = 0; kk < 64; kk += 32) {
      v8bf a = *(const v8bf*)&As2[(wv * 16 + lm) * 64 + kk + quad * 8];
#pragma unroll
      for (int j = 0; j < 16; ++j) {
        v8bf b = *(const v8bf*)&Bs2[(j * 16 + lm) * 64 + kk + quad * 8];
        acc[j] = __builtin_amdgcn_mfma_f32_16x16x32_bf16(a, b, acc[j], 0, 0, 0);
      }
    }
  }
#pragma unroll
  for (int j = 0; j < 16; ++j) {
    int nn = j * 16 + lm;
    float bb = b2[nn];
#pragma unroll
    for (int r = 0; r < 4; ++r) {
      int row = wv * 16 + quad * 4 + r;
      Hs[row * 257 + nn] = fmaxf(acc[j][r] + bb, 0.f);
    }
  }
  __syncthreads();
  for (int o = tid; o < 384; o += 256) {
    int hd = o >> 6, r = o & 63;
    int grow = r0 + r;
    float d = 0.f;
    if (hd < 2) {
      for (int k = 0; k < 256; ++k) d += Hs[r * 257 + k] * wcls[k * 2 + hd];
      d += bcls[hd];
      if (grow < NROI) out[grow * 2 + hd] = d;
    } else {
      int h4 = hd - 2;
      for (int k = 0; k < 256; ++k) d += Hs[r * 257 + k] * wreg[k * 4 + h4];
      d += breg[h4];
      if (grow < NROI) out[4000 + grow * 4 + h4] = d;
    }
  }
}

extern "C" void kernel_launch(void* const* d_in, const int* in_sizes, int n_in,
                              void* d_out, int out_size, void* d_ws, size_t ws_size,
                              hipStream_t stream) {
  const float* features = (const float*)d_in[0];
  const int* rois = (const int*)d_in[1];
  const float* w1 = (const float*)d_in[2];
  const float* b1 = (const float*)d_in[3];
  const float* w2 = (const float*)d_in[4];
  const float* b2 = (const float*)d_in[5];
  const float* wcls = (const float*)d_in[6];
  const float* bcls = (const float*)d_in[7];
  const float* wreg = (const float*)d_in[8];
  const float* breg = (const float*)d_in[9];
  char* ws = (char*)d_ws;
  ushort* ft  = (ushort*)(ws + 0);          // 57,802,752 B
  ushort* w1t = (ushort*)(ws + 57802752);   //  6,422,528 B
  ushort* w2t = (ushort*)(ws + 64225280);   //    131,072 B
  ushort* rf  = (ushort*)(ws + 64356352);   // 51,380,224 B (2048 rows; rows
                                            // 2000+ are GEMM padding)
  // perm lives in rf's padding rows (read by gemm1 as harmless tiny bf16)
  int*    perm = (int*)(ws + 64356352 + (size_t)NROI * KDIM * 2);
  float*  P   = (float*)(ws + 115736576);   // 29,360,128 B
  ushort* h1b = (ushort*)(ws + 145096704);  //  1,048,576 B
  float* out = (float*)d_out;

  hipLaunchKernelGGL(k_transpose, dim3(HWSZ / 128), dim3(256), 0, stream,
                     features, (uint*)ft);
  hipLaunchKernelGGL(k_prep, dim3(425), dim3(256), 0, stream,
                     w1, (uint*)w1t, w2, w2t, rois, perm);
  hipLaunchKernelGGL(k_pool, dim3(NROI * 7), dim3(64), 0, stream, rois, perm,
                     (const uint2*)ft, (uint2*)rf);
  hipLaunchKernelGGL(k_gemm1, dim3(32, 2, SPLITK), dim3(256), 0, stream, rf, w1t, P);
  hipLaunchKernelGGL(k_reduce, dim3(1024), dim3(256), 0, stream, P, b1, (uint*)h1b);
  hipLaunchKernelGGL(k_gemm2, dim3(32), dim3(256), 0, stream, h1b, w2t, b2, wcls, bcls, wreg, breg, out);
}

// Round 6
// 337.331 us; speedup vs baseline: 1.0455x; 1.0126x over previous
//
#include <hip/hip_runtime.h>

typedef unsigned int uint;
typedef unsigned short ushort;
typedef __bf16 v8bf __attribute__((ext_vector_type(8)));
typedef float v4f __attribute__((ext_vector_type(4)));
typedef float f2 __attribute__((ext_vector_type(2)));

#define CCH 256
#define HH 336
#define WW 336
#define HWSZ (HH*WW)
#define NROI 2000
#define KDIM 12544       // 49*256
#define MPAD 2048
#define SPLITK 14
#define KSP (KDIM/SPLITK)   // 896

__device__ __forceinline__ ushort bf16r(float f) {
  uint u = __float_as_uint(f);
  u += 0x7fffu + ((u >> 16) & 1u);   // RTNE
  return (ushort)(u >> 16);
}
__device__ __forceinline__ uint packbf(float a, float b) {
  return (uint)bf16r(a) | ((uint)bf16r(b) << 16);
}

typedef const __attribute__((address_space(1))) uint* gas_t;
typedef __attribute__((address_space(3))) uint* las_t;
__device__ __forceinline__ void async16(const void* g, void* l) {
  __builtin_amdgcn_global_load_lds((gas_t)g, (las_t)l, 16, 0, 0);
}

// features [256][336][336] fp32 -> ft [hw][c] bf16.
// v4: 128hw x 256ch tile; phase-1 float4/lane = 1KB/wave coalesced reads
// (was 256B/wave). LDS 128x134x4 = 68.6KB -> 2 blocks/CU. Phase-1 LDS b32
// writes are 8-way aliased but hide under the global-read pacing.
__global__ __launch_bounds__(256) void k_transpose(const float* __restrict__ f,
                                                   uint* __restrict__ ftu) {
  __shared__ uint T[128 * 134];
  int tid = threadIdx.x;
  int hw0 = blockIdx.x * 128;
  int hwq = tid & 31;             // hw-quad: hw = hw0 + hwq*4 .. +3
  int cp = tid >> 5;              // 0..7
#pragma unroll 2
  for (int j = 0; j < 16; ++j) {
    int cpair = j * 8 + cp;       // 0..127
    int c = cpair * 2;
    float4 fa = *(const float4*)&f[(size_t)c * HWSZ + hw0 + hwq * 4];
    float4 fb = *(const float4*)&f[(size_t)(c + 1) * HWSZ + hw0 + hwq * 4];
    T[(hwq * 4 + 0) * 134 + cpair] = packbf(fa.x, fb.x);
    T[(hwq * 4 + 1) * 134 + cpair] = packbf(fa.y, fb.y);
    T[(hwq * 4 + 2) * 134 + cpair] = packbf(fa.z, fb.z);
    T[(hwq * 4 + 3) * 134 + cpair] = packbf(fa.w, fb.w);
  }
  __syncthreads();
  int co = tid & 31, r = tid >> 5;   // 8 rows per iter
#pragma unroll 4
  for (int i = 0; i < 16; ++i) {
    int row = i * 8 + r;
    uint2 v0 = *(const uint2*)&T[row * 134 + co * 4];
    uint2 v1 = *(const uint2*)&T[row * 134 + co * 4 + 2];
    *(uint4*)(ftu + (size_t)(hw0 + row) * 128 + co * 4) =
        make_uint4(v0.x, v0.y, v1.x, v1.y);
  }
}

// Fused preprocessing: blocks 0..391 = w1perm, 392..423 = w2t, 424 = sort.
__global__ __launch_bounds__(256) void k_prep(const float* __restrict__ w1,
                                              uint* __restrict__ w1t_u,
                                              const float* __restrict__ w2,
                                              ushort* __restrict__ w2t,
                                              const int* __restrict__ rois,
                                              int* __restrict__ perm) {
  __shared__ ushort T[32][258];
  __shared__ int hist[64];
  __shared__ int keys[NROI];
  int tid = threadIdx.x;
  int b = blockIdx.x;
  if (b < 392) {
    // w1 [12544][256] fp32 (k=c*49+bin) -> w1t bf16 [n][k'], k'=bin*256+c
    int bin = b % 49;
    int c0 = (b / 49) * 32;
    int n = tid;
    for (int i = 0; i < 32; ++i)
      T[i][n] = bf16r(w1[(size_t)((c0 + i) * 49 + bin) * 256 + n]);
    __syncthreads();
    int cc = tid & 15;
    int nb = tid >> 4;
    for (int rep = 0; rep < 16; ++rep) {
      int nn = rep * 16 + nb;
      uint v = (uint)T[2 * cc][nn] | ((uint)T[2 * cc + 1][nn] << 16);
      w1t_u[(size_t)nn * (KDIM / 2) + bin * 128 + c0 / 2 + cc] = v;
    }
  } else if (b < 424) {
    // w2 [256][256] -> w2t bf16 [n][k]
    int n = (b - 392) * 8 + (tid >> 5);
    for (int kl = 0; kl < 8; ++kl) {
      int k = kl * 32 + (tid & 31);
      w2t[n * 256 + k] = bf16r(w2[k * 256 + n]);
    }
  } else {
    // counting-sort ROIs by spatial tile (8x8 grid of 42px) -> perm
    if (tid < 64) hist[tid] = 0;
    __syncthreads();
    for (int i = tid; i < NROI; i += 256) {
      int x1 = rois[i * 4 + 0], y1 = rois[i * 4 + 1];
      int x2 = rois[i * 4 + 2], y2 = rois[i * 4 + 3];
      int cx = (x1 + x2) >> 1, cy = (y1 + y2) >> 1;
      int k = (cy / 42) * 8 + (cx / 42);
      keys[i] = k;
      atomicAdd(&hist[k], 1);
    }
    __syncthreads();
    if (tid < 64) {               // wave-0 exclusive prefix scan
      int v = hist[tid];
      int s = v;
#pragma unroll
      for (int d = 1; d < 64; d <<= 1) {
        int t2 = __shfl_up(s, d, 64);
        if (tid >= d) s += t2;
      }
      hist[tid] = s - v;
    }
    __syncthreads();
    for (int i = tid; i < NROI; i += 256) {
      int pos = atomicAdd(&hist[keys[i]], 1);
      perm[pos] = i;
    }
  }
}

// Round-6: asm-pinned load batches. r5's C-level issue-then-consume was
// defeated by the compiler: with v[4][RH] (56 VGPR) live, LLVM sinks loads
// to their uses => ~1 load in flight at ~700cy L2-miss latency (unit
// residency ~45k cy for ~150 loads, invariant across r0-r5 structures).
// Fix: issue all 4*RH global_load_dwordx2 per chunk as VOLATILE inline asm
// (one base VGPR-pair per row + offset:0/512/1024/1536 immediates) --
// volatile can't be sunk/reordered -- then one s_waitcnt vmcnt(0) +
// sched_barrier(0) (rule 18: register-only consumers would otherwise hoist
// past the waitcnt), then the r5 prefix-walk consume, unchanged.
// Chunk cost ~ issue + 1 latency + consume ~ 1k cy; ~6 chunks/unit.
// Mapping/layout/bin math byte-identical to r5.
__device__ __forceinline__ void pkacc(f2& acc, uint u) {
  f2 t;
  t.x = __uint_as_float(u << 16);
  t.y = __uint_as_float(u & 0xffff0000u);
  asm("v_pk_add_f32 %0, %1, %0" : "+v"(acc) : "v"(t));
}
// accumulate uint2 (4 channels) into S[2]
#define UNPK2(S, u) do { pkacc(S[0], (u).x); pkacc(S[1], (u).y); } while (0)

#define GLOAD2(dst, ptr, OFF)                                        \
  asm volatile("global_load_dwordx2 %0, %1, off offset:" #OFF        \
               : "=v"(dst) : "v"(ptr))

template <int RH>
__device__ __forceinline__ void pool_unit(const uint2* __restrict__ ftu2,
                                          uint2* __restrict__ rfu2,
                                          int x1, int Lw, int ylo, int lane,
                                          uint ob) {
  const uint2* pr[RH];
#pragma unroll
  for (int r = 0; r < RH; ++r)
    pr[r] = ftu2 + (size_t)((ylo + r) * WW + x1) * 64 + lane;
  int xend = x1 + Lw;
  // bin-walk state (all wave-uniform scalars)
  int b = 0;
  int lo_cur = x1;
  int hi_cur = x1 + (Lw + 6) / 7;     // hi_0 = x1 + ceil(Lw/7)
  int lo_next = x1 + Lw / 7;          // lo_1
  f2 P[2], Lc[2], Ln[2];
  P[0] = (f2){0.f, 0.f}; P[1] = (f2){0.f, 0.f};
  Lc[0] = (f2){0.f, 0.f}; Lc[1] = (f2){0.f, 0.f};
  Ln[0] = (f2){0.f, 0.f}; Ln[1] = (f2){0.f, 0.f};
  const float invr = 1.0f / (float)RH;
  for (int xc = x1; xc < xend; xc += 4) {
    uint2 v[4][RH];
    // ---- issue phase: 4*RH independent loads, pinned by volatile asm ----
#pragma unroll
    for (int r = 0; r < RH; ++r) {
      GLOAD2(v[0][r], pr[r], 0);
      GLOAD2(v[1][r], pr[r], 512);
      GLOAD2(v[2][r], pr[r], 1024);
      GLOAD2(v[3][r], pr[r], 1536);
    }
    asm volatile("s_waitcnt vmcnt(0)" ::: "memory");
    __builtin_amdgcn_sched_barrier(0);
    // ---- consume phase (r5 prefix-walk, unchanged) ----
#pragma unroll
    for (int r = 0; r < RH; ++r) pr[r] += 256;   // advance 4 pixels
#pragma unroll
    for (int c = 0; c < 4; ++c) {
      int x = xc + c;
      if (x < xend) {
#pragma unroll
        for (int r = 0; r < RH; ++r) UNPK2(P, v[c][r]);
        int xp = x + 1;
        if (xp == lo_next) { Ln[0] = P[0]; Ln[1] = P[1]; }
        while (b < 7 && xp == hi_cur) {
          float inv = invr / (float)(hi_cur - lo_cur);
          uint2 o;
          o.x = packbf((P[0].x - Lc[0].x) * inv, (P[0].y - Lc[0].y) * inv);
          o.y = packbf((P[1].x - Lc[1].x) * inv, (P[1].y - Lc[1].y) * inv);
          rfu2[ob + b * 64] = o;
          ++b;
          Lc[0] = Ln[0]; Lc[1] = Ln[1];
          lo_cur = lo_next;
          hi_cur = x1 + ((b + 1) * Lw + 6) / 7;
          lo_next = x1 + ((b + 1) * Lw) / 7;
          if (xp == lo_next) { Ln[0] = P[0]; Ln[1] = P[1]; }
        }
      }
    }
  }
}

__global__ __launch_bounds__(64) void k_pool(const int* __restrict__ rois,
                                             const int* __restrict__ perm,
                                             const uint2* __restrict__ ftu2,
                                             uint2* __restrict__ rfu2) {
  int L = blockIdx.x;
  int i = L >> 3;
  int slot = (L & 7) * 250 + i / 7;
  int by = i % 7;
  int n = perm[slot];
  int lane = threadIdx.x;            // channel-quad 0..63
  int x1 = rois[n * 4 + 0], y1 = rois[n * 4 + 1];
  int x2 = rois[n * 4 + 2], y2 = rois[n * 4 + 3];
  int Lw = x2 - x1 + 1, Lh = y2 - y1 + 1;
  int ylo = y1 + (by * Lh) / 7;
  int yhi = y1 + ((by + 1) * Lh + 6) / 7;
  int rh = yhi - ylo;                // 1..7
  uint ob = ((uint)n * 49 + (uint)by * 7) * 64 + lane;
  switch (rh) {
    case 1: pool_unit<1>(ftu2, rfu2, x1, Lw, ylo, lane, ob); break;
    case 2: pool_unit<2>(ftu2, rfu2, x1, Lw, ylo, lane, ob); break;
    case 3: pool_unit<3>(ftu2, rfu2, x1, Lw, ylo, lane, ob); break;
    case 4: pool_unit<4>(ftu2, rfu2, x1, Lw, ylo, lane, ob); break;
    case 5: pool_unit<5>(ftu2, rfu2, x1, Lw, ylo, lane, ob); break;
    case 6: pool_unit<6>(ftu2, rfu2, x1, Lw, ylo, lane, ob); break;
    default: pool_unit<7>(ftu2, rfu2, x1, Lw, ylo, lane, ob); break;
  }
}

// NT GEMM: A=rf [2048][12544], B=w1t [256][12544], 64x128 tiles, split-K.
__global__ __launch_bounds__(256) void k_gemm1(const ushort* __restrict__ A,
                                               const ushort* __restrict__ B,
                                               float* __restrict__ P) {
  __shared__ ushort As[64 * 64];
  __shared__ ushort Bs[128 * 64];
  int m0 = blockIdx.x * 64;
  int n0 = blockIdx.y * 128;
  int ks = blockIdx.z;
  int k0 = ks * KSP;
  int tid = threadIdx.x;
  int lane = tid & 63, wv = tid >> 6;
  int wm = wv & 1, wn = wv >> 1;
  int lm = lane & 15, quad = lane >> 4;
  int srow = tid >> 3, scol = (tid & 7) * 8;
  v4f acc[2][4];
#pragma unroll
  for (int i = 0; i < 2; ++i)
#pragma unroll
    for (int j = 0; j < 4; ++j) acc[i][j] = (v4f){0.f, 0.f, 0.f, 0.f};
  const ushort* Ab = A + (size_t)(m0 + srow) * KDIM + k0 + scol;
  const ushort* Bb = B + (size_t)(n0 + srow) * KDIM + k0 + scol;
  for (int kt = 0; kt < KSP / 64; ++kt) {
    __syncthreads();
#pragma unroll
    for (int r = 0; r < 2; ++r)
      async16(Ab + (size_t)(r * 32) * KDIM + kt * 64, &As[(srow + r * 32) * 64 + scol]);
#pragma unroll
    for (int r = 0; r < 4; ++r)
      async16(Bb + (size_t)(r * 32) * KDIM + kt * 64, &Bs[(srow + r * 32) * 64 + scol]);
    __syncthreads();
#pragma unroll
    for (int kk = 0; kk < 64; kk += 32) {
      v8bf a[2], b[4];
#pragma unroll
      for (int i = 0; i < 2; ++i)
        a[i] = *(const v8bf*)&As[(wm * 32 + i * 16 + lm) * 64 + kk + quad * 8];
#pragma unroll
      for (int j = 0; j < 4; ++j)
        b[j] = *(const v8bf*)&Bs[(wn * 64 + j * 16 + lm) * 64 + kk + quad * 8];
#pragma unroll
      for (int i = 0; i < 2; ++i)
#pragma unroll
        for (int j = 0; j < 4; ++j)
          acc[i][j] = __builtin_amdgcn_mfma_f32_16x16x32_bf16(a[i], b[j], acc[i][j], 0, 0, 0);
    }
  }
  float* Pb = P + (size_t)ks * MPAD * 256;
#pragma unroll
  for (int i = 0; i < 2; ++i)
#pragma unroll
    for (int j = 0; j < 4; ++j) {
      int row = m0 + wm * 32 + i * 16 + quad * 4;
      int col = n0 + wn * 64 + j * 16 + lm;
#pragma unroll
      for (int r = 0; r < 4; ++r)
        Pb[(size_t)(row + r) * 256 + col] = acc[i][j][r];
    }
}

// sum split-K partials + bias + relu -> h1 bf16 [2048][256]
__global__ __launch_bounds__(256) void k_reduce(const float* __restrict__ P,
                                                const float* __restrict__ b1,
                                                uint* __restrict__ h1u) {
  int idx = blockIdx.x * 256 + threadIdx.x;  // < 2048*128
  int m = idx >> 7, np = idx & 127;
  const float2* Pp = (const float2*)P;
  float2 s = {0.f, 0.f};
#pragma unroll
  for (int ks = 0; ks < SPLITK; ++ks) {
    float2 v = Pp[(size_t)(ks * MPAD + m) * 128 + np];
    s.x += v.x; s.y += v.y;
  }
  s.x += b1[2 * np]; s.y += b1[2 * np + 1];
  s.x = fmaxf(s.x, 0.f); s.y = fmaxf(s.y, 0.f);
  h1u[idx] = packbf(s.x, s.y);
}

// GEMM2 (64 rows x full N=256, K=256) + fused cls/reg heads
__global__ __launch_bounds__(256) void k_gemm2(const ushort* __restrict__ h1b,
                                               const ushort* __restrict__ w2t,
                                               const float* __restrict__ b2,
                                               const float* __restrict__ wcls,
                                               const float* __restrict__ bcls,
                                               const float* __restrict__ wreg,
                                               const float* __restrict__ breg,
                                               float* __restrict__ out) {
  __shared__ ushort As2[64 * 64];
  __shared__ ushort Bs2[256 * 64];
  __shared__ float Hs[64 * 257];
  int tid = threadIdx.x;
  int r0 = blockIdx.x * 64;
  int lane = tid & 63, wv = tid >> 6;
  int lm = lane & 15, quad = lane >> 4;
  int srow = tid >> 3, scol = (tid & 7) * 8;
  v4f acc[16];
#pragma unroll
  for (int j = 0; j < 16; ++j) acc[j] = (v4f){0.f, 0.f, 0.f, 0.f};
  for (int kt = 0; kt < 4; ++kt) {
    __syncthreads();
#pragma unroll
    for (int r = 0; r < 2; ++r)
      async16(h1b + (size_t)(r0 + srow + r * 32) * 256 + kt * 64 + scol,
              &As2[(srow + r * 32) * 64 + scol]);
#pragma unroll
    for (int r = 0; r < 8; ++r)
      async16(w2t + (size_t)(srow + r * 32) * 256 + kt * 64 + scol,
              &Bs2[(srow + r * 32) * 64 + scol]);
    __syncthreads();
#pragma unroll
    for (int kk = 0; kk < 64; kk += 32) {
      v8bf a = *(const v8bf*)&As2[(wv * 16 + lm) * 64 + kk + quad * 8];
#pragma unroll
      for (int j = 0; j < 16; ++j) {
        v8bf b = *(const v8bf*)&Bs2[(j * 16 + lm) * 64 + kk + quad * 8];
        acc[j] = __builtin_amdgcn_mfma_f32_16x16x32_bf16(a, b, acc[j], 0, 0, 0);
      }
    }
  }
#pragma unroll
  for (int j = 0; j < 16; ++j) {
    int nn = j * 16 + lm;
    float bb = b2[nn];
#pragma unroll
    for (int r = 0; r < 4; ++r) {
      int row = wv * 16 + quad * 4 + r;
      Hs[row * 257 + nn] = fmaxf(acc[j][r] + bb, 0.f);
    }
  }
  __syncthreads();
  for (int o = tid; o < 384; o += 256) {
    int hd = o >> 6, r = o & 63;
    int grow = r0 + r;
    float d = 0.f;
    if (hd < 2) {
      for (int k = 0; k < 256; ++k) d += Hs[r * 257 + k] * wcls[k * 2 + hd];
      d += bcls[hd];
      if (grow < NROI) out[grow * 2 + hd] = d;
    } else {
      int h4 = hd - 2;
      for (int k = 0; k < 256; ++k) d += Hs[r * 257 + k] * wreg[k * 4 + h4];
      d += breg[h4];
      if (grow < NROI) out[4000 + grow * 4 + h4] = d;
    }
  }
}

extern "C" void kernel_launch(void* const* d_in, const int* in_sizes, int n_in,
                              void* d_out, int out_size, void* d_ws, size_t ws_size,
                              hipStream_t stream) {
  const float* features = (const float*)d_in[0];
  const int* rois = (const int*)d_in[1];
  const float* w1 = (const float*)d_in[2];
  const float* b1 = (const float*)d_in[3];
  const float* w2 = (const float*)d_in[4];
  const float* b2 = (const float*)d_in[5];
  const float* wcls = (const float*)d_in[6];
  const float* bcls = (const float*)d_in[7];
  const float* wreg = (const float*)d_in[8];
  const float* breg = (const float*)d_in[9];
  char* ws = (char*)d_ws;
  ushort* ft  = (ushort*)(ws + 0);          // 57,802,752 B
  ushort* w1t = (ushort*)(ws + 57802752);   //  6,422,528 B
  ushort* w2t = (ushort*)(ws + 64225280);   //    131,072 B
  ushort* rf  = (ushort*)(ws + 64356352);   // 51,380,224 B (2048 rows; rows
                                            // 2000+ are GEMM padding)
  // perm lives in rf's padding rows (read by gemm1 as harmless tiny bf16)
  int*    perm = (int*)(ws + 64356352 + (size_t)NROI * KDIM * 2);
  float*  P   = (float*)(ws + 115736576);   // 29,360,128 B
  ushort* h1b = (ushort*)(ws + 145096704);  //  1,048,576 B
  float* out = (float*)d_out;

  hipLaunchKernelGGL(k_transpose, dim3(HWSZ / 128), dim3(256), 0, stream,
                     features, (uint*)ft);
  hipLaunchKernelGGL(k_prep, dim3(425), dim3(256), 0, stream,
                     w1, (uint*)w1t, w2, w2t, rois, perm);
  hipLaunchKernelGGL(k_pool, dim3(NROI * 7), dim3(64), 0, stream, rois, perm,
                     (const uint2*)ft, (uint2*)rf);
  hipLaunchKernelGGL(k_gemm1, dim3(32, 2, SPLITK), dim3(256), 0, stream, rf, w1t, P);
  hipLaunchKernelGGL(k_reduce, dim3(1024), dim3(256), 0, stream, P, b1, (uint*)h1b);
  hipLaunchKernelGGL(k_gemm2, dim3(32), dim3(256), 0, stream, h1b, w2t, b2, wcls, bcls, wreg, breg, out);
}

// Round 7
// 332.372 us; speedup vs baseline: 1.0611x; 1.0149x over previous
//
#include <hip/hip_runtime.h>

typedef unsigned int uint;
typedef unsigned short ushort;
typedef __bf16 v8bf __attribute__((ext_vector_type(8)));
typedef float v4f __attribute__((ext_vector_type(4)));
typedef float f2 __attribute__((ext_vector_type(2)));
typedef float f4v __attribute__((ext_vector_type(4)));

#define CCH 256
#define HH 336
#define WW 336
#define HWSZ (HH*WW)
#define NROI 2000
#define KDIM 12544       // 49*256
#define MPAD 2048
#define SPLITK 14
#define KSP (KDIM/SPLITK)   // 896

__device__ __forceinline__ ushort bf16r(float f) {
  uint u = __float_as_uint(f);
  u += 0x7fffu + ((u >> 16) & 1u);   // RTNE
  return (ushort)(u >> 16);
}
__device__ __forceinline__ uint packbf(float a, float b) {
  return (uint)bf16r(a) | ((uint)bf16r(b) << 16);
}

typedef const __attribute__((address_space(1))) uint* gas_t;
typedef __attribute__((address_space(3))) uint* las_t;
__device__ __forceinline__ void async16(const void* g, void* l) {
  __builtin_amdgcn_global_load_lds((gas_t)g, (las_t)l, 16, 0, 0);
}

// Round-7: k_transpose rebuilt for latency/occupancy (measured: 70us,
// occ 16%, VALU 4.8%, HBM 20%, 3.6M LDS conflicts => nothing busy).
//  (1) tile 64px x 256ch: LDS 64*128*4 = 32KB exact -> 4-5 blocks/CU
//      (was 68.6KB -> 2).
//  (2) all 16 global_load_dwordx4 per thread issued as volatile asm
//      (r6-proven: C-level batches get sunk by regalloc), one
//      vmcnt(0)+sched_barrier, then unpack. ~4KB/CU in flight.
//  (3) LDS stride 128 + XOR swizzle col ^= ((row>>2)&7)<<2 : phase-1
//      writes land 2 lanes/bank (free); phase-2 reads apply the same
//      involution (XOR on bits 2..4 of uint index keeps 16B alignment
//      and uint4 contiguity); global stores stay linear -> ftu bytes
//      identical to all previous rounds.
#define GLOAD4(dst, ptr)                                             \
  asm volatile("global_load_dwordx4 %0, %1, off" : "=v"(dst) : "v"(ptr))

__global__ __launch_bounds__(256) void k_transpose(const float* __restrict__ f,
                                                   uint* __restrict__ ftu) {
  __shared__ uint T[64 * 128];    // 32 KB
  int tid = threadIdx.x;
  int hw0 = blockIdx.x * 64;
  int hwq = tid & 15;             // hw-quad: pixels hw0+hwq*4 .. +3
  int cp = tid >> 4;              // 0..15
  const float* base = f + hw0 + hwq * 4;
  f4v va[8], vb[8];
#pragma unroll
  for (int j = 0; j < 8; ++j) {
    int cpair = j * 16 + cp;      // 0..127
    const float* pa = base + (size_t)(2 * cpair) * HWSZ;
    GLOAD4(va[j], pa);
    GLOAD4(vb[j], pa + HWSZ);
  }
  asm volatile("s_waitcnt vmcnt(0)" ::: "memory");
  __builtin_amdgcn_sched_barrier(0);
  int sw = (hwq & 7) << 2;        // swizzle for rows hwq*4..hwq*4+3
#pragma unroll
  for (int j = 0; j < 8; ++j) {
    int cs = (j * 16 + cp) ^ sw;
    T[(hwq * 4 + 0) * 128 + cs] = packbf(va[j].x, vb[j].x);
    T[(hwq * 4 + 1) * 128 + cs] = packbf(va[j].y, vb[j].y);
    T[(hwq * 4 + 2) * 128 + cs] = packbf(va[j].z, vb[j].z);
    T[(hwq * 4 + 3) * 128 + cs] = packbf(va[j].w, vb[j].w);
  }
  __syncthreads();
  int co = tid & 31, r = tid >> 5;   // 8 rows per iter
#pragma unroll
  for (int i = 0; i < 8; ++i) {
    int row = i * 8 + r;
    int col = (co * 4) ^ (((row >> 2) & 7) << 2);   // inverse swizzle
    uint4 v = *(const uint4*)&T[row * 128 + col];
    *(uint4*)(ftu + (size_t)(hw0 + row) * 128 + co * 4) = v;
  }
}

// Fused preprocessing: blocks 0..391 = w1perm, 392..423 = w2t, 424 = sort.
__global__ __launch_bounds__(256) void k_prep(const float* __restrict__ w1,
                                              uint* __restrict__ w1t_u,
                                              const float* __restrict__ w2,
                                              ushort* __restrict__ w2t,
                                              const int* __restrict__ rois,
                                              int* __restrict__ perm) {
  __shared__ ushort T[32][258];
  __shared__ int hist[64];
  __shared__ int keys[NROI];
  int tid = threadIdx.x;
  int b = blockIdx.x;
  if (b < 392) {
    // w1 [12544][256] fp32 (k=c*49+bin) -> w1t bf16 [n][k'], k'=bin*256+c
    int bin = b % 49;
    int c0 = (b / 49) * 32;
    int n = tid;
    for (int i = 0; i < 32; ++i)
      T[i][n] = bf16r(w1[(size_t)((c0 + i) * 49 + bin) * 256 + n]);
    __syncthreads();
    int cc = tid & 15;
    int nb = tid >> 4;
    for (int rep = 0; rep < 16; ++rep) {
      int nn = rep * 16 + nb;
      uint v = (uint)T[2 * cc][nn] | ((uint)T[2 * cc + 1][nn] << 16);
      w1t_u[(size_t)nn * (KDIM / 2) + bin * 128 + c0 / 2 + cc] = v;
    }
  } else if (b < 424) {
    // w2 [256][256] -> w2t bf16 [n][k]
    int n = (b - 392) * 8 + (tid >> 5);
    for (int kl = 0; kl < 8; ++kl) {
      int k = kl * 32 + (tid & 31);
      w2t[n * 256 + k] = bf16r(w2[k * 256 + n]);
    }
  } else {
    // counting-sort ROIs by spatial tile (8x8 grid of 42px) -> perm
    if (tid < 64) hist[tid] = 0;
    __syncthreads();
    for (int i = tid; i < NROI; i += 256) {
      int x1 = rois[i * 4 + 0], y1 = rois[i * 4 + 1];
      int x2 = rois[i * 4 + 2], y2 = rois[i * 4 + 3];
      int cx = (x1 + x2) >> 1, cy = (y1 + y2) >> 1;
      int k = (cy / 42) * 8 + (cx / 42);
      keys[i] = k;
      atomicAdd(&hist[k], 1);
    }
    __syncthreads();
    if (tid < 64) {               // wave-0 exclusive prefix scan
      int v = hist[tid];
      int s = v;
#pragma unroll
      for (int d = 1; d < 64; d <<= 1) {
        int t2 = __shfl_up(s, d, 64);
        if (tid >= d) s += t2;
      }
      hist[tid] = s - v;
    }
    __syncthreads();
    for (int i = tid; i < NROI; i += 256) {
      int pos = atomicAdd(&hist[keys[i]], 1);
      perm[pos] = i;
    }
  }
}

// k_pool (r6): asm-pinned load batches, prefix-walk bin closing.
__device__ __forceinline__ void pkacc(f2& acc, uint u) {
  f2 t;
  t.x = __uint_as_float(u << 16);
  t.y = __uint_as_float(u & 0xffff0000u);
  asm("v_pk_add_f32 %0, %1, %0" : "+v"(acc) : "v"(t));
}
// accumulate uint2 (4 channels) into S[2]
#define UNPK2(S, u) do { pkacc(S[0], (u).x); pkacc(S[1], (u).y); } while (0)

#define GLOAD2(dst, ptr, OFF)                                        \
  asm volatile("global_load_dwordx2 %0, %1, off offset:" #OFF        \
               : "=v"(dst) : "v"(ptr))

template <int RH>
__device__ __forceinline__ void pool_unit(const uint2* __restrict__ ftu2,
                                          uint2* __restrict__ rfu2,
                                          int x1, int Lw, int ylo, int lane,
                                          uint ob) {
  const uint2* pr[RH];
#pragma unroll
  for (int r = 0; r < RH; ++r)
    pr[r] = ftu2 + (size_t)((ylo + r) * WW + x1) * 64 + lane;
  int xend = x1 + Lw;
  // bin-walk state (all wave-uniform scalars)
  int b = 0;
  int lo_cur = x1;
  int hi_cur = x1 + (Lw + 6) / 7;     // hi_0 = x1 + ceil(Lw/7)
  int lo_next = x1 + Lw / 7;          // lo_1
  f2 P[2], Lc[2], Ln[2];
  P[0] = (f2){0.f, 0.f}; P[1] = (f2){0.f, 0.f};
  Lc[0] = (f2){0.f, 0.f}; Lc[1] = (f2){0.f, 0.f};
  Ln[0] = (f2){0.f, 0.f}; Ln[1] = (f2){0.f, 0.f};
  const float invr = 1.0f / (float)RH;
  for (int xc = x1; xc < xend; xc += 4) {
    uint2 v[4][RH];
    // ---- issue phase: 4*RH independent loads, pinned by volatile asm ----
#pragma unroll
    for (int r = 0; r < RH; ++r) {
      GLOAD2(v[0][r], pr[r], 0);
      GLOAD2(v[1][r], pr[r], 512);
      GLOAD2(v[2][r], pr[r], 1024);
      GLOAD2(v[3][r], pr[r], 1536);
    }
    asm volatile("s_waitcnt vmcnt(0)" ::: "memory");
    __builtin_amdgcn_sched_barrier(0);
    // ---- consume phase (r5 prefix-walk, unchanged) ----
#pragma unroll
    for (int r = 0; r < RH; ++r) pr[r] += 256;   // advance 4 pixels
#pragma unroll
    for (int c = 0; c < 4; ++c) {
      int x = xc + c;
      if (x < xend) {
#pragma unroll
        for (int r = 0; r < RH; ++r) UNPK2(P, v[c][r]);
        int xp = x + 1;
        if (xp == lo_next) { Ln[0] = P[0]; Ln[1] = P[1]; }
        while (b < 7 && xp == hi_cur) {
          float inv = invr / (float)(hi_cur - lo_cur);
          uint2 o;
          o.x = packbf((P[0].x - Lc[0].x) * inv, (P[0].y - Lc[0].y) * inv);
          o.y = packbf((P[1].x - Lc[1].x) * inv, (P[1].y - Lc[1].y) * inv);
          rfu2[ob + b * 64] = o;
          ++b;
          Lc[0] = Ln[0]; Lc[1] = Ln[1];
          lo_cur = lo_next;
          hi_cur = x1 + ((b + 1) * Lw + 6) / 7;
          lo_next = x1 + ((b + 1) * Lw) / 7;
          if (xp == lo_next) { Ln[0] = P[0]; Ln[1] = P[1]; }
        }
      }
    }
  }
}

__global__ __launch_bounds__(64) void k_pool(const int* __restrict__ rois,
                                             const int* __restrict__ perm,
                                             const uint2* __restrict__ ftu2,
                                             uint2* __restrict__ rfu2) {
  int L = blockIdx.x;
  int i = L >> 3;
  int slot = (L & 7) * 250 + i / 7;
  int by = i % 7;
  int n = perm[slot];
  int lane = threadIdx.x;            // channel-quad 0..63
  int x1 = rois[n * 4 + 0], y1 = rois[n * 4 + 1];
  int x2 = rois[n * 4 + 2], y2 = rois[n * 4 + 3];
  int Lw = x2 - x1 + 1, Lh = y2 - y1 + 1;
  int ylo = y1 + (by * Lh) / 7;
  int yhi = y1 + ((by + 1) * Lh + 6) / 7;
  int rh = yhi - ylo;                // 1..7
  uint ob = ((uint)n * 49 + (uint)by * 7) * 64 + lane;
  switch (rh) {
    case 1: pool_unit<1>(ftu2, rfu2, x1, Lw, ylo, lane, ob); break;
    case 2: pool_unit<2>(ftu2, rfu2, x1, Lw, ylo, lane, ob); break;
    case 3: pool_unit<3>(ftu2, rfu2, x1, Lw, ylo, lane, ob); break;
    case 4: pool_unit<4>(ftu2, rfu2, x1, Lw, ylo, lane, ob); break;
    case 5: pool_unit<5>(ftu2, rfu2, x1, Lw, ylo, lane, ob); break;
    case 6: pool_unit<6>(ftu2, rfu2, x1, Lw, ylo, lane, ob); break;
    default: pool_unit<7>(ftu2, rfu2, x1, Lw, ylo, lane, ob); break;
  }
}

// NT GEMM: A=rf [2048][12544], B=w1t [256][12544], 64x128 tiles, split-K.
__global__ __launch_bounds__(256) void k_gemm1(const ushort* __restrict__ A,
                                               const ushort* __restrict__ B,
                                               float* __restrict__ P) {
  __shared__ ushort As[64 * 64];
  __shared__ ushort Bs[128 * 64];
  int m0 = blockIdx.x * 64;
  int n0 = blockIdx.y * 128;
  int ks = blockIdx.z;
  int k0 = ks * KSP;
  int tid = threadIdx.x;
  int lane = tid & 63, wv = tid >> 6;
  int wm = wv & 1, wn = wv >> 1;
  int lm = lane & 15, quad = lane >> 4;
  int srow = tid >> 3, scol = (tid & 7) * 8;
  v4f acc[2][4];
#pragma unroll
  for (int i = 0; i < 2; ++i)
#pragma unroll
    for (int j = 0; j < 4; ++j) acc[i][j] = (v4f){0.f, 0.f, 0.f, 0.f};
  const ushort* Ab = A + (size_t)(m0 + srow) * KDIM + k0 + scol;
  const ushort* Bb = B + (size_t)(n0 + srow) * KDIM + k0 + scol;
  for (int kt = 0; kt < KSP / 64; ++kt) {
    __syncthreads();
#pragma unroll
    for (int r = 0; r < 2; ++r)
      async16(Ab + (size_t)(r * 32) * KDIM + kt * 64, &As[(srow + r * 32) * 64 + scol]);
#pragma unroll
    for (int r = 0; r < 4; ++r)
      async16(Bb + (size_t)(r * 32) * KDIM + kt * 64, &Bs[(srow + r * 32) * 64 + scol]);
    __syncthreads();
#pragma unroll
    for (int kk = 0; kk < 64; kk += 32) {
      v8bf a[2], b[4];
#pragma unroll
      for (int i = 0; i < 2; ++i)
        a[i] = *(const v8bf*)&As[(wm * 32 + i * 16 + lm) * 64 + kk + quad * 8];
#pragma unroll
      for (int j = 0; j < 4; ++j)
        b[j] = *(const v8bf*)&Bs[(wn * 64 + j * 16 + lm) * 64 + kk + quad * 8];
#pragma unroll
      for (int i = 0; i < 2; ++i)
#pragma unroll
        for (int j = 0; j < 4; ++j)
          acc[i][j] = __builtin_amdgcn_mfma_f32_16x16x32_bf16(a[i], b[j], acc[i][j], 0, 0, 0);
    }
  }
  float* Pb = P + (size_t)ks * MPAD * 256;
#pragma unroll
  for (int i = 0; i < 2; ++i)
#pragma unroll
    for (int j = 0; j < 4; ++j) {
      int row = m0 + wm * 32 + i * 16 + quad * 4;
      int col = n0 + wn * 64 + j * 16 + lm;
#pragma unroll
      for (int r = 0; r < 4; ++r)
        Pb[(size_t)(row + r) * 256 + col] = acc[i][j][r];
    }
}

// sum split-K partials + bias + relu -> h1 bf16 [2048][256]
__global__ __launch_bounds__(256) void k_reduce(const float* __restrict__ P,
                                                const float* __restrict__ b1,
                                                uint* __restrict__ h1u) {
  int idx = blockIdx.x * 256 + threadIdx.x;  // < 2048*128
  int m = idx >> 7, np = idx & 127;
  const float2* Pp = (const float2*)P;
  float2 s = {0.f, 0.f};
#pragma unroll
  for (int ks = 0; ks < SPLITK; ++ks) {
    float2 v = Pp[(size_t)(ks * MPAD + m) * 128 + np];
    s.x += v.x; s.y += v.y;
  }
  s.x += b1[2 * np]; s.y += b1[2 * np + 1];
  s.x = fmaxf(s.x, 0.f); s.y = fmaxf(s.y, 0.f);
  h1u[idx] = packbf(s.x, s.y);
}

// GEMM2 (64 rows x full N=256, K=256) + fused cls/reg heads
__global__ __launch_bounds__(256) void k_gemm2(const ushort* __restrict__ h1b,
                                               const ushort* __restrict__ w2t,
                                               const float* __restrict__ b2,
                                               const float* __restrict__ wcls,
                                               const float* __restrict__ bcls,
                                               const float* __restrict__ wreg,
                                               const float* __restrict__ breg,
                                               float* __restrict__ out) {
  __shared__ ushort As2[64 * 64];
  __shared__ ushort Bs2[256 * 64];
  __shared__ float Hs[64 * 257];
  int tid = threadIdx.x;
  int r0 = blockIdx.x * 64;
  int lane = tid & 63, wv = tid >> 6;
  int lm = lane & 15, quad = lane >> 4;
  int srow = tid >> 3, scol = (tid & 7) * 8;
  v4f acc[16];
#pragma unroll
  for (int j = 0; j < 16; ++j) acc[j] = (v4f){0.f, 0.f, 0.f, 0.f};
  for (int kt = 0; kt < 4; ++kt) {
    __syncthreads();
#pragma unroll
    for (int r = 0; r < 2; ++r)
      async16(h1b + (size_t)(r0 + srow + r * 32) * 256 + kt * 64 + scol,
              &As2[(srow + r * 32) * 64 + scol]);
#pragma unroll
    for (int r = 0; r < 8; ++r)
      async16(w2t + (size_t)(srow + r * 32) * 256 + kt * 64 + scol,
              &Bs2[(srow + r * 32) * 64 + scol]);
    __syncthreads();
#pragma unroll
    for (int kk = 0; kk < 64; kk += 32) {
      v8bf a = *(const v8bf*)&As2[(wv * 16 + lm) * 64 + kk + quad * 8];
#pragma unroll
      for (int j = 0; j < 16; ++j) {
        v8bf b = *(const v8bf*)&Bs2[(j * 16 + lm) * 64 + kk + quad * 8];
        acc[j] = __builtin_amdgcn_mfma_f32_16x16x32_bf16(a, b, acc[j], 0, 0, 0);
      }
    }
  }
#pragma unroll
  for (int j = 0; j < 16; ++j) {
    int nn = j * 16 + lm;
    float bb = b2[nn];
#pragma unroll
    for (int r = 0; r < 4; ++r) {
      int row = wv * 16 + quad * 4 + r;
      Hs[row * 257 + nn] = fmaxf(acc[j][r] + bb, 0.f);
    }
  }
  __syncthreads();
  for (int o = tid; o < 384; o += 256) {
    int hd = o >> 6, r = o & 63;
    int grow = r0 + r;
    float d = 0.f;
    if (hd < 2) {
      for (int k = 0; k < 256; ++k) d += Hs[r * 257 + k] * wcls[k * 2 + hd];
      d += bcls[hd];
      if (grow < NROI) out[grow * 2 + hd] = d;
    } else {
      int h4 = hd - 2;
      for (int k = 0; k < 256; ++k) d += Hs[r * 257 + k] * wreg[k * 4 + h4];
      d += breg[h4];
      if (grow < NROI) out[4000 + grow * 4 + h4] = d;
    }
  }
}

extern "C" void kernel_launch(void* const* d_in, const int* in_sizes, int n_in,
                              void* d_out, int out_size, void* d_ws, size_t ws_size,
                              hipStream_t stream) {
  const float* features = (const float*)d_in[0];
  const int* rois = (const int*)d_in[1];
  const float* w1 = (const float*)d_in[2];
  const float* b1 = (const float*)d_in[3];
  const float* w2 = (const float*)d_in[4];
  const float* b2 = (const float*)d_in[5];
  const float* wcls = (const float*)d_in[6];
  const float* bcls = (const float*)d_in[7];
  const float* wreg = (const float*)d_in[8];
  const float* breg = (const float*)d_in[9];
  char* ws = (char*)d_ws;
  ushort* ft  = (ushort*)(ws + 0);          // 57,802,752 B
  ushort* w1t = (ushort*)(ws + 57802752);   //  6,422,528 B
  ushort* w2t = (ushort*)(ws + 64225280);   //    131,072 B
  ushort* rf  = (ushort*)(ws + 64356352);   // 51,380,224 B (2048 rows; rows
                                            // 2000+ are GEMM padding)
  // perm lives in rf's padding rows (read by gemm1 as harmless tiny bf16)
  int*    perm = (int*)(ws + 64356352 + (size_t)NROI * KDIM * 2);
  float*  P   = (float*)(ws + 115736576);   // 29,360,128 B
  ushort* h1b = (ushort*)(ws + 145096704);  //  1,048,576 B
  float* out = (float*)d_out;

  hipLaunchKernelGGL(k_transpose, dim3(HWSZ / 64), dim3(256), 0, stream,
                     features, (uint*)ft);
  hipLaunchKernelGGL(k_prep, dim3(425), dim3(256), 0, stream,
                     w1, (uint*)w1t, w2, w2t, rois, perm);
  hipLaunchKernelGGL(k_pool, dim3(NROI * 7), dim3(64), 0, stream, rois, perm,
                     (const uint2*)ft, (uint2*)rf);
  hipLaunchKernelGGL(k_gemm1, dim3(32, 2, SPLITK), dim3(256), 0, stream, rf, w1t, P);
  hipLaunchKernelGGL(k_reduce, dim3(1024), dim3(256), 0, stream, P, b1, (uint*)h1b);
  hipLaunchKernelGGL(k_gemm2, dim3(32), dim3(256), 0, stream, h1b, w2t, b2, wcls, bcls, wreg, breg, out);
}

// Round 8
// 330.955 us; speedup vs baseline: 1.0656x; 1.0043x over previous
//
#include <hip/hip_runtime.h>

typedef unsigned int uint;
typedef unsigned short ushort;
typedef __bf16 v8bf __attribute__((ext_vector_type(8)));
typedef float v4f __attribute__((ext_vector_type(4)));
typedef float f2 __attribute__((ext_vector_type(2)));
typedef float f4v __attribute__((ext_vector_type(4)));

#define CCH 256
#define HH 336
#define WW 336
#define HWSZ (HH*WW)
#define NROI 2000
#define KDIM 12544       // 49*256
#define MPAD 2048
#define SPLITK 7
#define KSP (KDIM/SPLITK)   // 1792
#define NTRB (HWSZ/64)      // 1764 transpose blocks

__device__ __forceinline__ ushort bf16r(float f) {
  uint u = __float_as_uint(f);
  u += 0x7fffu + ((u >> 16) & 1u);   // RTNE
  return (ushort)(u >> 16);
}
__device__ __forceinline__ uint packbf(float a, float b) {
  return (uint)bf16r(a) | ((uint)bf16r(b) << 16);
}

typedef const __attribute__((address_space(1))) uint* gas_t;
typedef __attribute__((address_space(3))) uint* las_t;
__device__ __forceinline__ void async16(const void* g, void* l) {
  __builtin_amdgcn_global_load_lds((gas_t)g, (las_t)l, 16, 0, 0);
}

#define GLOAD4(dst, ptr)                                             \
  asm volatile("global_load_dwordx4 %0, %1, off" : "=v"(dst) : "v"(ptr))

// Round-8: k_transpose + k_prep merged into one launch (prep is data-
// independent of transpose; its blocks fill transpose's latency stalls and
// one launch boundary disappears). Blocks 0..1763 = transpose (r7 body,
// unchanged); 1764..2155 = w1 perm; 2156..2187 = w2t; 2188 = ROI sort.
// LDS: one 32KB pool, aliased per branch.
__global__ __launch_bounds__(256) void k_trprep(const float* __restrict__ f,
                                                uint* __restrict__ ftu,
                                                const float* __restrict__ w1,
                                                uint* __restrict__ w1t_u,
                                                const float* __restrict__ w2,
                                                ushort* __restrict__ w2t,
                                                const int* __restrict__ rois,
                                                int* __restrict__ perm) {
  __shared__ uint SM[64 * 128];   // 32 KB shared pool
  int tid = threadIdx.x;
  if (blockIdx.x < NTRB) {
    // ---- transpose: features [256][336][336] fp32 -> ft [hw][c] bf16 ----
    uint* T = SM;
    int hw0 = blockIdx.x * 64;
    int hwq = tid & 15;             // hw-quad: pixels hw0+hwq*4 .. +3
    int cp = tid >> 4;              // 0..15
    const float* base = f + hw0 + hwq * 4;
    f4v va[8], vb[8];
#pragma unroll
    for (int j = 0; j < 8; ++j) {
      int cpair = j * 16 + cp;      // 0..127
      const float* pa = base + (size_t)(2 * cpair) * HWSZ;
      GLOAD4(va[j], pa);
      GLOAD4(vb[j], pa + HWSZ);
    }
    asm volatile("s_waitcnt vmcnt(0)" ::: "memory");
    __builtin_amdgcn_sched_barrier(0);
    int sw = (hwq & 7) << 2;        // swizzle for rows hwq*4..hwq*4+3
#pragma unroll
    for (int j = 0; j < 8; ++j) {
      int cs = (j * 16 + cp) ^ sw;
      T[(hwq * 4 + 0) * 128 + cs] = packbf(va[j].x, vb[j].x);
      T[(hwq * 4 + 1) * 128 + cs] = packbf(va[j].y, vb[j].y);
      T[(hwq * 4 + 2) * 128 + cs] = packbf(va[j].z, vb[j].z);
      T[(hwq * 4 + 3) * 128 + cs] = packbf(va[j].w, vb[j].w);
    }
    __syncthreads();
    int co = tid & 31, r = tid >> 5;   // 8 rows per iter
#pragma unroll
    for (int i = 0; i < 8; ++i) {
      int row = i * 8 + r;
      int col = (co * 4) ^ (((row >> 2) & 7) << 2);   // inverse swizzle
      uint4 v = *(const uint4*)&T[row * 128 + col];
      *(uint4*)(ftu + (size_t)(hw0 + row) * 128 + co * 4) = v;
    }
    return;
  }
  int b = blockIdx.x - NTRB;        // 0..424
  if (b < 392) {
    // w1 [12544][256] fp32 (k=c*49+bin) -> w1t bf16 [n][k'], k'=bin*256+c
    ushort (*T)[258] = reinterpret_cast<ushort (*)[258]>(SM);  // 16512 B
    int bin = b % 49;
    int c0 = (b / 49) * 32;
    int n = tid;
    for (int i = 0; i < 32; ++i)
      T[i][n] = bf16r(w1[(size_t)((c0 + i) * 49 + bin) * 256 + n]);
    __syncthreads();
    int cc = tid & 15;
    int nb = tid >> 4;
    for (int rep = 0; rep < 16; ++rep) {
      int nn = rep * 16 + nb;
      uint v = (uint)T[2 * cc][nn] | ((uint)T[2 * cc + 1][nn] << 16);
      w1t_u[(size_t)nn * (KDIM / 2) + bin * 128 + c0 / 2 + cc] = v;
    }
  } else if (b < 424) {
    // w2 [256][256] -> w2t bf16 [n][k]
    int n = (b - 392) * 8 + (tid >> 5);
    for (int kl = 0; kl < 8; ++kl) {
      int k = kl * 32 + (tid & 31);
      w2t[n * 256 + k] = bf16r(w2[k * 256 + n]);
    }
  } else {
    // counting-sort ROIs by spatial tile (8x8 grid of 42px) -> perm
    int* hist = (int*)((char*)SM + 16512);   // 256 B
    int* keys = hist + 64;                   // 8000 B (ends 24768 < 32768)
    if (tid < 64) hist[tid] = 0;
    __syncthreads();
    for (int i = tid; i < NROI; i += 256) {
      int x1 = rois[i * 4 + 0], y1 = rois[i * 4 + 1];
      int x2 = rois[i * 4 + 2], y2 = rois[i * 4 + 3];
      int cx = (x1 + x2) >> 1, cy = (y1 + y2) >> 1;
      int k = (cy / 42) * 8 + (cx / 42);
      keys[i] = k;
      atomicAdd(&hist[k], 1);
    }
    __syncthreads();
    if (tid < 64) {               // wave-0 exclusive prefix scan
      int v = hist[tid];
      int s = v;
#pragma unroll
      for (int d = 1; d < 64; d <<= 1) {
        int t2 = __shfl_up(s, d, 64);
        if (tid >= d) s += t2;
      }
      hist[tid] = s - v;
    }
    __syncthreads();
    for (int i = tid; i < NROI; i += 256) {
      int pos = atomicAdd(&hist[keys[i]], 1);
      perm[pos] = i;
    }
  }
}

// k_pool (r6): asm-pinned load batches, prefix-walk bin closing.
__device__ __forceinline__ void pkacc(f2& acc, uint u) {
  f2 t;
  t.x = __uint_as_float(u << 16);
  t.y = __uint_as_float(u & 0xffff0000u);
  asm("v_pk_add_f32 %0, %1, %0" : "+v"(acc) : "v"(t));
}
// accumulate uint2 (4 channels) into S[2]
#define UNPK2(S, u) do { pkacc(S[0], (u).x); pkacc(S[1], (u).y); } while (0)

#define GLOAD2(dst, ptr, OFF)                                        \
  asm volatile("global_load_dwordx2 %0, %1, off offset:" #OFF        \
               : "=v"(dst) : "v"(ptr))

template <int RH>
__device__ __forceinline__ void pool_unit(const uint2* __restrict__ ftu2,
                                          uint2* __restrict__ rfu2,
                                          int x1, int Lw, int ylo, int lane,
                                          uint ob) {
  const uint2* pr[RH];
#pragma unroll
  for (int r = 0; r < RH; ++r)
    pr[r] = ftu2 + (size_t)((ylo + r) * WW + x1) * 64 + lane;
  int xend = x1 + Lw;
  // bin-walk state (all wave-uniform scalars)
  int b = 0;
  int lo_cur = x1;
  int hi_cur = x1 + (Lw + 6) / 7;     // hi_0 = x1 + ceil(Lw/7)
  int lo_next = x1 + Lw / 7;          // lo_1
  f2 P[2], Lc[2], Ln[2];
  P[0] = (f2){0.f, 0.f}; P[1] = (f2){0.f, 0.f};
  Lc[0] = (f2){0.f, 0.f}; Lc[1] = (f2){0.f, 0.f};
  Ln[0] = (f2){0.f, 0.f}; Ln[1] = (f2){0.f, 0.f};
  const float invr = 1.0f / (float)RH;
  for (int xc = x1; xc < xend; xc += 4) {
    uint2 v[4][RH];
    // ---- issue phase: 4*RH independent loads, pinned by volatile asm ----
#pragma unroll
    for (int r = 0; r < RH; ++r) {
      GLOAD2(v[0][r], pr[r], 0);
      GLOAD2(v[1][r], pr[r], 512);
      GLOAD2(v[2][r], pr[r], 1024);
      GLOAD2(v[3][r], pr[r], 1536);
    }
    asm volatile("s_waitcnt vmcnt(0)" ::: "memory");
    __builtin_amdgcn_sched_barrier(0);
    // ---- consume phase (r5 prefix-walk, unchanged) ----
#pragma unroll
    for (int r = 0; r < RH; ++r) pr[r] += 256;   // advance 4 pixels
#pragma unroll
    for (int c = 0; c < 4; ++c) {
      int x = xc + c;
      if (x < xend) {
#pragma unroll
        for (int r = 0; r < RH; ++r) UNPK2(P, v[c][r]);
        int xp = x + 1;
        if (xp == lo_next) { Ln[0] = P[0]; Ln[1] = P[1]; }
        while (b < 7 && xp == hi_cur) {
          float inv = invr / (float)(hi_cur - lo_cur);
          uint2 o;
          o.x = packbf((P[0].x - Lc[0].x) * inv, (P[0].y - Lc[0].y) * inv);
          o.y = packbf((P[1].x - Lc[1].x) * inv, (P[1].y - Lc[1].y) * inv);
          rfu2[ob + b * 64] = o;
          ++b;
          Lc[0] = Ln[0]; Lc[1] = Ln[1];
          lo_cur = lo_next;
          hi_cur = x1 + ((b + 1) * Lw + 6) / 7;
          lo_next = x1 + ((b + 1) * Lw) / 7;
          if (xp == lo_next) { Ln[0] = P[0]; Ln[1] = P[1]; }
        }
      }
    }
  }
}

__global__ __launch_bounds__(64) void k_pool(const int* __restrict__ rois,
                                             const int* __restrict__ perm,
                                             const uint2* __restrict__ ftu2,
                                             uint2* __restrict__ rfu2) {
  int L = blockIdx.x;
  int i = L >> 3;
  int slot = (L & 7) * 250 + i / 7;
  int by = i % 7;
  int n = perm[slot];
  int lane = threadIdx.x;            // channel-quad 0..63
  int x1 = rois[n * 4 + 0], y1 = rois[n * 4 + 1];
  int x2 = rois[n * 4 + 2], y2 = rois[n * 4 + 3];
  int Lw = x2 - x1 + 1, Lh = y2 - y1 + 1;
  int ylo = y1 + (by * Lh) / 7;
  int yhi = y1 + ((by + 1) * Lh + 6) / 7;
  int rh = yhi - ylo;                // 1..7
  uint ob = ((uint)n * 49 + (uint)by * 7) * 64 + lane;
  switch (rh) {
    case 1: pool_unit<1>(ftu2, rfu2, x1, Lw, ylo, lane, ob); break;
    case 2: pool_unit<2>(ftu2, rfu2, x1, Lw, ylo, lane, ob); break;
    case 3: pool_unit<3>(ftu2, rfu2, x1, Lw, ylo, lane, ob); break;
    case 4: pool_unit<4>(ftu2, rfu2, x1, Lw, ylo, lane, ob); break;
    case 5: pool_unit<5>(ftu2, rfu2, x1, Lw, ylo, lane, ob); break;
    case 6: pool_unit<6>(ftu2, rfu2, x1, Lw, ylo, lane, ob); break;
    default: pool_unit<7>(ftu2, rfu2, x1, Lw, ylo, lane, ob); break;
  }
}

// NT GEMM: A=rf [2048][12544], B=w1t [256][12544], 64x128 tiles, split-K=7
// (halved from 14: P traffic 29.4->14.7 MB each way; 448 blocks still
// 1.75/CU; per-block K doubles to 28 kt-iters for barrier amortization).
__global__ __launch_bounds__(256) void k_gemm1(const ushort* __restrict__ A,
                                               const ushort* __restrict__ B,
                                               float* __restrict__ P) {
  __shared__ ushort As[64 * 64];
  __shared__ ushort Bs[128 * 64];
  int m0 = blockIdx.x * 64;
  int n0 = blockIdx.y * 128;
  int ks = blockIdx.z;
  int k0 = ks * KSP;
  int tid = threadIdx.x;
  int lane = tid & 63, wv = tid >> 6;
  int wm = wv & 1, wn = wv >> 1;
  int lm = lane & 15, quad = lane >> 4;
  int srow = tid >> 3, scol = (tid & 7) * 8;
  v4f acc[2][4];
#pragma unroll
  for (int i = 0; i < 2; ++i)
#pragma unroll
    for (int j = 0; j < 4; ++j) acc[i][j] = (v4f){0.f, 0.f, 0.f, 0.f};
  const ushort* Ab = A + (size_t)(m0 + srow) * KDIM + k0 + scol;
  const ushort* Bb = B + (size_t)(n0 + srow) * KDIM + k0 + scol;
  for (int kt = 0; kt < KSP / 64; ++kt) {
    __syncthreads();
#pragma unroll
    for (int r = 0; r < 2; ++r)
      async16(Ab + (size_t)(r * 32) * KDIM + kt * 64, &As[(srow + r * 32) * 64 + scol]);
#pragma unroll
    for (int r = 0; r < 4; ++r)
      async16(Bb + (size_t)(r * 32) * KDIM + kt * 64, &Bs[(srow + r * 32) * 64 + scol]);
    __syncthreads();
#pragma unroll
    for (int kk = 0; kk < 64; kk += 32) {
      v8bf a[2], b[4];
#pragma unroll
      for (int i = 0; i < 2; ++i)
        a[i] = *(const v8bf*)&As[(wm * 32 + i * 16 + lm) * 64 + kk + quad * 8];
#pragma unroll
      for (int j = 0; j < 4; ++j)
        b[j] = *(const v8bf*)&Bs[(wn * 64 + j * 16 + lm) * 64 + kk + quad * 8];
#pragma unroll
      for (int i = 0; i < 2; ++i)
#pragma unroll
        for (int j = 0; j < 4; ++j)
          acc[i][j] = __builtin_amdgcn_mfma_f32_16x16x32_bf16(a[i], b[j], acc[i][j], 0, 0, 0);
    }
  }
  float* Pb = P + (size_t)ks * MPAD * 256;
#pragma unroll
  for (int i = 0; i < 2; ++i)
#pragma unroll
    for (int j = 0; j < 4; ++j) {
      int row = m0 + wm * 32 + i * 16 + quad * 4;
      int col = n0 + wn * 64 + j * 16 + lm;
#pragma unroll
      for (int r = 0; r < 4; ++r)
        Pb[(size_t)(row + r) * 256 + col] = acc[i][j][r];
    }
}

// GEMM2 with fused split-K reduce (k_reduce eliminated): A-tile = sum of 7
// P-partials + b1 + relu, packed bf16 into XOR-swizzled LDS (2-way banks on
// write AND the MFMA v8bf read: chunk ^= row&7 on 16B granules). Then the
// unchanged K=256 MFMA loop + cls/reg heads.
__global__ __launch_bounds__(256) void k_gemm2(const float* __restrict__ P,
                                               const float* __restrict__ b1,
                                               const ushort* __restrict__ w2t,
                                               const float* __restrict__ b2,
                                               const float* __restrict__ wcls,
                                               const float* __restrict__ bcls,
                                               const float* __restrict__ wreg,
                                               const float* __restrict__ breg,
                                               float* __restrict__ out) {
  __shared__ ushort HsA[64 * 256];   // 32 KB swizzled A (bf16)
  __shared__ ushort Bs2[256 * 64];
  __shared__ float Hs[64 * 257];
  int tid = threadIdx.x;
  int r0 = blockIdx.x * 64;
  int lane = tid & 63, wv = tid >> 6;
  int lm = lane & 15, quad = lane >> 4;
  int srow = tid >> 3, scol = (tid & 7) * 8;
  // ---- stage A: split-K sum + b1 + relu -> bf16 LDS ----
  uint* H = (uint*)HsA;
  for (int it = 0; it < 16; ++it) {
    int e = it * 256 + tid;          // 0..4095
    int row = e >> 6;                // 0..63
    int c4 = e & 63;                 // float4 column (16B = 4 ch)
    float4 s = {0.f, 0.f, 0.f, 0.f};
#pragma unroll
    for (int ks = 0; ks < SPLITK; ++ks) {
      float4 v = ((const float4*)P)[((size_t)ks * MPAD + r0 + row) * 64 + c4];
      s.x += v.x; s.y += v.y; s.z += v.z; s.w += v.w;
    }
    int col = c4 * 4;
    s.x = fmaxf(s.x + b1[col + 0], 0.f);
    s.y = fmaxf(s.y + b1[col + 1], 0.f);
    s.z = fmaxf(s.z + b1[col + 2], 0.f);
    s.w = fmaxf(s.w + b1[col + 3], 0.f);
    int cs = (c4 >> 1) ^ (row & 7);            // 16B-chunk swizzle
    int ui = row * 128 + cs * 4 + (c4 & 1) * 2;
    H[ui]     = packbf(s.x, s.y);
    H[ui + 1] = packbf(s.z, s.w);
  }
  v4f acc[16];
#pragma unroll
  for (int j = 0; j < 16; ++j) acc[j] = (v4f){0.f, 0.f, 0.f, 0.f};
  int arow = wv * 16 + lm;
  int asw = (arow & 7) << 3;         // ushort-index swizzle (8 bf16 = 16B)
  for (int kt = 0; kt < 4; ++kt) {
    __syncthreads();
#pragma unroll
    for (int r = 0; r < 8; ++r)
      async16(w2t + (size_t)(srow + r * 32) * 256 + kt * 64 + scol,
              &Bs2[(srow + r * 32) * 64 + scol]);
    __syncthreads();
#pragma unroll
    for (int kk = 0; kk < 64; kk += 32) {
      v8bf a = *(const v8bf*)&HsA[arow * 256 + ((kt * 64 + kk + quad * 8) ^ asw)];
#pragma unroll
      for (int j = 0; j < 16; ++j) {
        v8bf b = *(const v8bf*)&Bs2[(j * 16 + lm) * 64 + kk + quad * 8];
        acc[j] = __builtin_amdgcn_mfma_f32_16x16x32_bf16(a, b, acc[j], 0, 0, 0);
      }
    }
  }
#pragma unroll
  for (int j = 0; j < 16; ++j) {
    int nn = j * 16 + lm;
    float bb = b2[nn];
#pragma unroll
    for (int r = 0; r < 4; ++r) {
      int row = wv * 16 + quad * 4 + r;
      Hs[row * 257 + nn] = fmaxf(acc[j][r] + bb, 0.f);
    }
  }
  __syncthreads();
  for (int o = tid; o < 384; o += 256) {
    int hd = o >> 6, r = o & 63;
    int grow = r0 + r;
    float d = 0.f;
    if (hd < 2) {
      for (int k = 0; k < 256; ++k) d += Hs[r * 257 + k] * wcls[k * 2 + hd];
      d += bcls[hd];
      if (grow < NROI) out[grow * 2 + hd] = d;
    } else {
      int h4 = hd - 2;
      for (int k = 0; k < 256; ++k) d += Hs[r * 257 + k] * wreg[k * 4 + h4];
      d += breg[h4];
      if (grow < NROI) out[4000 + grow * 4 + h4] = d;
    }
  }
}

extern "C" void kernel_launch(void* const* d_in, const int* in_sizes, int n_in,
                              void* d_out, int out_size, void* d_ws, size_t ws_size,
                              hipStream_t stream) {
  const float* features = (const float*)d_in[0];
  const int* rois = (const int*)d_in[1];
  const float* w1 = (const float*)d_in[2];
  const float* b1 = (const float*)d_in[3];
  const float* w2 = (const float*)d_in[4];
  const float* b2 = (const float*)d_in[5];
  const float* wcls = (const float*)d_in[6];
  const float* bcls = (const float*)d_in[7];
  const float* wreg = (const float*)d_in[8];
  const float* breg = (const float*)d_in[9];
  char* ws = (char*)d_ws;
  ushort* ft  = (ushort*)(ws + 0);          // 57,802,752 B
  ushort* w1t = (ushort*)(ws + 57802752);   //  6,422,528 B
  ushort* w2t = (ushort*)(ws + 64225280);   //    131,072 B
  ushort* rf  = (ushort*)(ws + 64356352);   // 51,380,224 B (2048 rows; rows
                                            // 2000+ are GEMM padding)
  // perm lives in rf's padding rows (read by gemm1 as harmless tiny bf16)
  int*    perm = (int*)(ws + 64356352 + (size_t)NROI * KDIM * 2);
  float*  P   = (float*)(ws + 115736576);   // 14,680,064 B used (of 29.4 MB)
  float* out = (float*)d_out;

  hipLaunchKernelGGL(k_trprep, dim3(NTRB + 425), dim3(256), 0, stream,
                     features, (uint*)ft, w1, (uint*)w1t, w2, w2t, rois, perm);
  hipLaunchKernelGGL(k_pool, dim3(NROI * 7), dim3(64), 0, stream, rois, perm,
                     (const uint2*)ft, (uint2*)rf);
  hipLaunchKernelGGL(k_gemm1, dim3(32, 2, SPLITK), dim3(256), 0, stream, rf, w1t, P);
  hipLaunchKernelGGL(k_gemm2, dim3(32), dim3(256), 0, stream, P, b1, w2t, b2,
                     wcls, bcls, wreg, breg, out);
}

// Round 9
// 330.459 us; speedup vs baseline: 1.0672x; 1.0015x over previous
//
#include <hip/hip_runtime.h>

typedef unsigned int uint;
typedef unsigned short ushort;
typedef __bf16 v8bf __attribute__((ext_vector_type(8)));
typedef float v4f __attribute__((ext_vector_type(4)));
typedef float f2 __attribute__((ext_vector_type(2)));
typedef float f4v __attribute__((ext_vector_type(4)));

#define CCH 256
#define HH 336
#define WW 336
#define HWSZ (HH*WW)
#define NROI 2000
#define KDIM 12544       // 49*256
#define MPAD 2048
#define SPLITK 7
#define KSP (KDIM/SPLITK)   // 1792
#define NTRB (HWSZ/64)      // 1764 transpose blocks

__device__ __forceinline__ ushort bf16r(float f) {
  uint u = __float_as_uint(f);
  u += 0x7fffu + ((u >> 16) & 1u);   // RTNE
  return (ushort)(u >> 16);
}
__device__ __forceinline__ uint packbf(float a, float b) {
  return (uint)bf16r(a) | ((uint)bf16r(b) << 16);
}

typedef const __attribute__((address_space(1))) uint* gas_t;
typedef __attribute__((address_space(3))) uint* las_t;
__device__ __forceinline__ void async16(const void* g, void* l) {
  __builtin_amdgcn_global_load_lds((gas_t)g, (las_t)l, 16, 0, 0);
}

#define GLOAD4(dst, ptr)                                             \
  asm volatile("global_load_dwordx4 %0, %1, off" : "=v"(dst) : "v"(ptr))

// Round-8: k_transpose + k_prep merged (blocks 0..1763 transpose,
// 1764..2155 w1 perm, 2156..2187 w2t, 2188 ROI sort). 32KB LDS pool.
__global__ __launch_bounds__(256) void k_trprep(const float* __restrict__ f,
                                                uint* __restrict__ ftu,
                                                const float* __restrict__ w1,
                                                uint* __restrict__ w1t_u,
                                                const float* __restrict__ w2,
                                                ushort* __restrict__ w2t,
                                                const int* __restrict__ rois,
                                                int* __restrict__ perm) {
  __shared__ uint SM[64 * 128];   // 32 KB shared pool
  int tid = threadIdx.x;
  if (blockIdx.x < NTRB) {
    // ---- transpose: features [256][336][336] fp32 -> ft [hw][c] bf16 ----
    uint* T = SM;
    int hw0 = blockIdx.x * 64;
    int hwq = tid & 15;             // hw-quad: pixels hw0+hwq*4 .. +3
    int cp = tid >> 4;              // 0..15
    const float* base = f + hw0 + hwq * 4;
    f4v va[8], vb[8];
#pragma unroll
    for (int j = 0; j < 8; ++j) {
      int cpair = j * 16 + cp;      // 0..127
      const float* pa = base + (size_t)(2 * cpair) * HWSZ;
      GLOAD4(va[j], pa);
      GLOAD4(vb[j], pa + HWSZ);
    }
    asm volatile("s_waitcnt vmcnt(0)" ::: "memory");
    __builtin_amdgcn_sched_barrier(0);
    int sw = (hwq & 7) << 2;        // swizzle for rows hwq*4..hwq*4+3
#pragma unroll
    for (int j = 0; j < 8; ++j) {
      int cs = (j * 16 + cp) ^ sw;
      T[(hwq * 4 + 0) * 128 + cs] = packbf(va[j].x, vb[j].x);
      T[(hwq * 4 + 1) * 128 + cs] = packbf(va[j].y, vb[j].y);
      T[(hwq * 4 + 2) * 128 + cs] = packbf(va[j].z, vb[j].z);
      T[(hwq * 4 + 3) * 128 + cs] = packbf(va[j].w, vb[j].w);
    }
    __syncthreads();
    int co = tid & 31, r = tid >> 5;   // 8 rows per iter
#pragma unroll
    for (int i = 0; i < 8; ++i) {
      int row = i * 8 + r;
      int col = (co * 4) ^ (((row >> 2) & 7) << 2);   // inverse swizzle
      uint4 v = *(const uint4*)&T[row * 128 + col];
      *(uint4*)(ftu + (size_t)(hw0 + row) * 128 + co * 4) = v;
    }
    return;
  }
  int b = blockIdx.x - NTRB;        // 0..424
  if (b < 392) {
    // w1 [12544][256] fp32 (k=c*49+bin) -> w1t bf16 [n][k'], k'=bin*256+c
    ushort (*T)[258] = reinterpret_cast<ushort (*)[258]>(SM);  // 16512 B
    int bin = b % 49;
    int c0 = (b / 49) * 32;
    int n = tid;
    for (int i = 0; i < 32; ++i)
      T[i][n] = bf16r(w1[(size_t)((c0 + i) * 49 + bin) * 256 + n]);
    __syncthreads();
    int cc = tid & 15;
    int nb = tid >> 4;
    for (int rep = 0; rep < 16; ++rep) {
      int nn = rep * 16 + nb;
      uint v = (uint)T[2 * cc][nn] | ((uint)T[2 * cc + 1][nn] << 16);
      w1t_u[(size_t)nn * (KDIM / 2) + bin * 128 + c0 / 2 + cc] = v;
    }
  } else if (b < 424) {
    // w2 [256][256] -> w2t bf16 [n][k]
    int n = (b - 392) * 8 + (tid >> 5);
    for (int kl = 0; kl < 8; ++kl) {
      int k = kl * 32 + (tid & 31);
      w2t[n * 256 + k] = bf16r(w2[k * 256 + n]);
    }
  } else {
    // counting-sort ROIs by spatial tile (8x8 grid of 42px) -> perm
    int* hist = (int*)((char*)SM + 16512);   // 256 B
    int* keys = hist + 64;                   // 8000 B (ends 24768 < 32768)
    if (tid < 64) hist[tid] = 0;
    __syncthreads();
    for (int i = tid; i < NROI; i += 256) {
      int x1 = rois[i * 4 + 0], y1 = rois[i * 4 + 1];
      int x2 = rois[i * 4 + 2], y2 = rois[i * 4 + 3];
      int cx = (x1 + x2) >> 1, cy = (y1 + y2) >> 1;
      int k = (cy / 42) * 8 + (cx / 42);
      keys[i] = k;
      atomicAdd(&hist[k], 1);
    }
    __syncthreads();
    if (tid < 64) {               // wave-0 exclusive prefix scan
      int v = hist[tid];
      int s = v;
#pragma unroll
      for (int d = 1; d < 64; d <<= 1) {
        int t2 = __shfl_up(s, d, 64);
        if (tid >= d) s += t2;
      }
      hist[tid] = s - v;
    }
    __syncthreads();
    for (int i = tid; i < NROI; i += 256) {
      int pos = atomicAdd(&hist[keys[i]], 1);
      perm[pos] = i;
    }
  }
}

// Round-9 k_pool: depth-2 pipelined chunks (counted vmcnt, T3/T4 style).
// r6's vmcnt(0)-per-chunk was a depth-1 stop-and-go: ~700cy latency + ~150cy
// consume per chunk, ~80% stall for small RH. Now: ping-pong two register
// chunk-buffers; issue chunk k+1, s_waitcnt vmcnt(CW*RH) (chunk k done,
// k+1 in flight), sched_barrier(0), consume k. Stores inside consume only
// make the counted wait conservative (FIFO), never incorrect.
// Per-RH config keeps kernel VGPR <= ~110 (<=128 preserves 4 waves/SIMD):
//   RH 1-2: CW=8 double-buffered (64 regs of buffer)
//   RH 3-4: CW=4 double-buffered (48/64 regs)
//   RH 5-7: CW=4 single-buffer (r6 behavior; consume ~ latency already)
__device__ __forceinline__ void pkacc(f2& acc, uint u) {
  f2 t;
  t.x = __uint_as_float(u << 16);
  t.y = __uint_as_float(u & 0xffff0000u);
  asm("v_pk_add_f32 %0, %1, %0" : "+v"(acc) : "v"(t));
}
#define UNPK2(S, u) do { pkacc(S[0], (u).x); pkacc(S[1], (u).y); } while (0)

#define GL(dst, ptr, OFF)                                            \
  asm volatile("global_load_dwordx2 %0, %1, off offset:" #OFF        \
               : "=v"(dst) : "v"(ptr))

template <int N> __device__ __forceinline__ void waitvm() {
  if constexpr (N == 0)       asm volatile("s_waitcnt vmcnt(0)" ::: "memory");
  else if constexpr (N == 8)  asm volatile("s_waitcnt vmcnt(8)" ::: "memory");
  else if constexpr (N == 12) asm volatile("s_waitcnt vmcnt(12)" ::: "memory");
  else if constexpr (N == 16) asm volatile("s_waitcnt vmcnt(16)" ::: "memory");
  else                        asm volatile("s_waitcnt vmcnt(0)" ::: "memory");
}

struct BinState {
  int b, lo_cur, hi_cur, lo_next;
  f2 P[2], Lc[2], Ln[2];
};

template <int RH, int CW>
__device__ __forceinline__ void issue_chunk(uint2 (&buf)[CW][RH],
                                            const uint2* (&pr)[RH]) {
#pragma unroll
  for (int r = 0; r < RH; ++r) {
    GL(buf[0][r], pr[r], 0);
    if constexpr (CW > 1) GL(buf[1][r], pr[r], 512);
    if constexpr (CW > 2) GL(buf[2][r], pr[r], 1024);
    if constexpr (CW > 3) GL(buf[3][r], pr[r], 1536);
    if constexpr (CW > 4) GL(buf[4][r], pr[r], 2048);
    if constexpr (CW > 5) GL(buf[5][r], pr[r], 2560);
    if constexpr (CW > 6) GL(buf[6][r], pr[r], 3072);
    if constexpr (CW > 7) GL(buf[7][r], pr[r], 3584);
  }
#pragma unroll
  for (int r = 0; r < RH; ++r) pr[r] += CW * 64;
}

template <int RH, int CW>
__device__ __forceinline__ void consume_chunk(const uint2 (&v)[CW][RH], int xc,
                                              int xend, int x1, int Lw,
                                              float invr, uint ob,
                                              uint2* __restrict__ rfu2,
                                              BinState& S) {
#pragma unroll
  for (int c = 0; c < CW; ++c) {
    int x = xc + c;
    if (x < xend) {
#pragma unroll
      for (int r = 0; r < RH; ++r) UNPK2(S.P, v[c][r]);
      int xp = x + 1;
      if (xp == S.lo_next) { S.Ln[0] = S.P[0]; S.Ln[1] = S.P[1]; }
      while (S.b < 7 && xp == S.hi_cur) {
        float inv = invr / (float)(S.hi_cur - S.lo_cur);
        uint2 o;
        o.x = packbf((S.P[0].x - S.Lc[0].x) * inv, (S.P[0].y - S.Lc[0].y) * inv);
        o.y = packbf((S.P[1].x - S.Lc[1].x) * inv, (S.P[1].y - S.Lc[1].y) * inv);
        rfu2[ob + S.b * 64] = o;
        ++S.b;
        S.Lc[0] = S.Ln[0]; S.Lc[1] = S.Ln[1];
        S.lo_cur = S.lo_next;
        S.hi_cur = x1 + ((S.b + 1) * Lw + 6) / 7;
        S.lo_next = x1 + ((S.b + 1) * Lw) / 7;
        if (xp == S.lo_next) { S.Ln[0] = S.P[0]; S.Ln[1] = S.P[1]; }
      }
    }
  }
}

template <int RH>
__device__ __forceinline__ void init_state(BinState& S, int x1, int Lw) {
  S.b = 0;
  S.lo_cur = x1;
  S.hi_cur = x1 + (Lw + 6) / 7;
  S.lo_next = x1 + Lw / 7;
  S.P[0] = (f2){0.f, 0.f}; S.P[1] = (f2){0.f, 0.f};
  S.Lc[0] = (f2){0.f, 0.f}; S.Lc[1] = (f2){0.f, 0.f};
  S.Ln[0] = (f2){0.f, 0.f}; S.Ln[1] = (f2){0.f, 0.f};
}

// depth-2 double-buffered walk
template <int RH, int CW>
__device__ void pool_db(const uint2* __restrict__ ftu2,
                        uint2* __restrict__ rfu2,
                        int x1, int Lw, int ylo, int lane, uint ob) {
  const uint2* pr[RH];
#pragma unroll
  for (int r = 0; r < RH; ++r)
    pr[r] = ftu2 + (size_t)((ylo + r) * WW + x1) * 64 + lane;
  int xend = x1 + Lw;
  BinState S;
  init_state<RH>(S, x1, Lw);
  const float invr = 1.0f / (float)RH;
  uint2 va[CW][RH], vb[CW][RH];
  issue_chunk<RH, CW>(va, pr);
  int xc = x1;
  for (;;) {
    int xn = xc + CW;
    if (xn < xend) { issue_chunk<RH, CW>(vb, pr); waitvm<CW * RH>(); }
    else waitvm<0>();
    __builtin_amdgcn_sched_barrier(0);
    consume_chunk<RH, CW>(va, xc, xend, x1, Lw, invr, ob, rfu2, S);
    if (xn >= xend) return;
    xc = xn;
    xn = xc + CW;
    if (xn < xend) { issue_chunk<RH, CW>(va, pr); waitvm<CW * RH>(); }
    else waitvm<0>();
    __builtin_amdgcn_sched_barrier(0);
    consume_chunk<RH, CW>(vb, xc, xend, x1, Lw, invr, ob, rfu2, S);
    if (xn >= xend) return;
    xc = xn;
  }
}

// depth-1 single-buffer walk (r6 behavior) for large RH
template <int RH, int CW>
__device__ void pool_sb(const uint2* __restrict__ ftu2,
                        uint2* __restrict__ rfu2,
                        int x1, int Lw, int ylo, int lane, uint ob) {
  const uint2* pr[RH];
#pragma unroll
  for (int r = 0; r < RH; ++r)
    pr[r] = ftu2 + (size_t)((ylo + r) * WW + x1) * 64 + lane;
  int xend = x1 + Lw;
  BinState S;
  init_state<RH>(S, x1, Lw);
  const float invr = 1.0f / (float)RH;
  uint2 va[CW][RH];
  for (int xc = x1; xc < xend; xc += CW) {
    issue_chunk<RH, CW>(va, pr);
    waitvm<0>();
    __builtin_amdgcn_sched_barrier(0);
    consume_chunk<RH, CW>(va, xc, xend, x1, Lw, invr, ob, rfu2, S);
  }
}

__global__ __launch_bounds__(64) void k_pool(const int* __restrict__ rois,
                                             const int* __restrict__ perm,
                                             const uint2* __restrict__ ftu2,
                                             uint2* __restrict__ rfu2) {
  int L = blockIdx.x;
  int i = L >> 3;
  int slot = (L & 7) * 250 + i / 7;
  int by = i % 7;
  int n = perm[slot];
  int lane = threadIdx.x;            // channel-quad 0..63
  int x1 = rois[n * 4 + 0], y1 = rois[n * 4 + 1];
  int x2 = rois[n * 4 + 2], y2 = rois[n * 4 + 3];
  int Lw = x2 - x1 + 1, Lh = y2 - y1 + 1;
  int ylo = y1 + (by * Lh) / 7;
  int yhi = y1 + ((by + 1) * Lh + 6) / 7;
  int rh = yhi - ylo;                // 1..7
  uint ob = ((uint)n * 49 + (uint)by * 7) * 64 + lane;
  switch (rh) {
    case 1: pool_db<1, 8>(ftu2, rfu2, x1, Lw, ylo, lane, ob); break;
    case 2: pool_db<2, 8>(ftu2, rfu2, x1, Lw, ylo, lane, ob); break;
    case 3: pool_db<3, 4>(ftu2, rfu2, x1, Lw, ylo, lane, ob); break;
    case 4: pool_db<4, 4>(ftu2, rfu2, x1, Lw, ylo, lane, ob); break;
    case 5: pool_sb<5, 4>(ftu2, rfu2, x1, Lw, ylo, lane, ob); break;
    case 6: pool_sb<6, 4>(ftu2, rfu2, x1, Lw, ylo, lane, ob); break;
    default: pool_sb<7, 4>(ftu2, rfu2, x1, Lw, ylo, lane, ob); break;
  }
}

// NT GEMM: A=rf [2048][12544], B=w1t [256][12544], 64x128 tiles, split-K=7
__global__ __launch_bounds__(256) void k_gemm1(const ushort* __restrict__ A,
                                               const ushort* __restrict__ B,
                                               float* __restrict__ P) {
  __shared__ ushort As[64 * 64];
  __shared__ ushort Bs[128 * 64];
  int m0 = blockIdx.x * 64;
  int n0 = blockIdx.y * 128;
  int ks = blockIdx.z;
  int k0 = ks * KSP;
  int tid = threadIdx.x;
  int lane = tid & 63, wv = tid >> 6;
  int wm = wv & 1, wn = wv >> 1;
  int lm = lane & 15, quad = lane >> 4;
  int srow = tid >> 3, scol = (tid & 7) * 8;
  v4f acc[2][4];
#pragma unroll
  for (int i = 0; i < 2; ++i)
#pragma unroll
    for (int j = 0; j < 4; ++j) acc[i][j] = (v4f){0.f, 0.f, 0.f, 0.f};
  const ushort* Ab = A + (size_t)(m0 + srow) * KDIM + k0 + scol;
  const ushort* Bb = B + (size_t)(n0 + srow) * KDIM + k0 + scol;
  for (int kt = 0; kt < KSP / 64; ++kt) {
    __syncthreads();
#pragma unroll
    for (int r = 0; r < 2; ++r)
      async16(Ab + (size_t)(r * 32) * KDIM + kt * 64, &As[(srow + r * 32) * 64 + scol]);
#pragma unroll
    for (int r = 0; r < 4; ++r)
      async16(Bb + (size_t)(r * 32) * KDIM + kt * 64, &Bs[(srow + r * 32) * 64 + scol]);
    __syncthreads();
#pragma unroll
    for (int kk = 0; kk < 64; kk += 32) {
      v8bf a[2], b[4];
#pragma unroll
      for (int i = 0; i < 2; ++i)
        a[i] = *(const v8bf*)&As[(wm * 32 + i * 16 + lm) * 64 + kk + quad * 8];
#pragma unroll
      for (int j = 0; j < 4; ++j)
        b[j] = *(const v8bf*)&Bs[(wn * 64 + j * 16 + lm) * 64 + kk + quad * 8];
#pragma unroll
      for (int i = 0; i < 2; ++i)
#pragma unroll
        for (int j = 0; j < 4; ++j)
          acc[i][j] = __builtin_amdgcn_mfma_f32_16x16x32_bf16(a[i], b[j], acc[i][j], 0, 0, 0);
    }
  }
  float* Pb = P + (size_t)ks * MPAD * 256;
#pragma unroll
  for (int i = 0; i < 2; ++i)
#pragma unroll
    for (int j = 0; j < 4; ++j) {
      int row = m0 + wm * 32 + i * 16 + quad * 4;
      int col = n0 + wn * 64 + j * 16 + lm;
#pragma unroll
      for (int r = 0; r < 4; ++r)
        Pb[(size_t)(row + r) * 256 + col] = acc[i][j][r];
    }
}

// GEMM2 with fused split-K reduce: A-tile = sum of 7 P-partials + b1 + relu,
// packed bf16 into XOR-swizzled LDS; then K=256 MFMA loop + cls/reg heads.
__global__ __launch_bounds__(256) void k_gemm2(const float* __restrict__ P,
                                               const float* __restrict__ b1,
                                               const ushort* __restrict__ w2t,
                                               const float* __restrict__ b2,
                                               const float* __restrict__ wcls,
                                               const float* __restrict__ bcls,
                                               const float* __restrict__ wreg,
                                               const float* __restrict__ breg,
                                               float* __restrict__ out) {
  __shared__ ushort HsA[64 * 256];   // 32 KB swizzled A (bf16)
  __shared__ ushort Bs2[256 * 64];
  __shared__ float Hs[64 * 257];
  int tid = threadIdx.x;
  int r0 = blockIdx.x * 64;
  int lane = tid & 63, wv = tid >> 6;
  int lm = lane & 15, quad = lane >> 4;
  int srow = tid >> 3, scol = (tid & 7) * 8;
  // ---- stage A: split-K sum + b1 + relu -> bf16 LDS ----
  uint* H = (uint*)HsA;
  for (int it = 0; it < 16; ++it) {
    int e = it * 256 + tid;          // 0..4095
    int row = e >> 6;                // 0..63
    int c4 = e & 63;                 // float4 column (16B = 4 ch)
    float4 s = {0.f, 0.f, 0.f, 0.f};
#pragma unroll
    for (int ks = 0; ks < SPLITK; ++ks) {
      float4 v = ((const float4*)P)[((size_t)ks * MPAD + r0 + row) * 64 + c4];
      s.x += v.x; s.y += v.y; s.z += v.z; s.w += v.w;
    }
    int col = c4 * 4;
    s.x = fmaxf(s.x + b1[col + 0], 0.f);
    s.y = fmaxf(s.y + b1[col + 1], 0.f);
    s.z = fmaxf(s.z + b1[col + 2], 0.f);
    s.w = fmaxf(s.w + b1[col + 3], 0.f);
    int cs = (c4 >> 1) ^ (row & 7);            // 16B-chunk swizzle
    int ui = row * 128 + cs * 4 + (c4 & 1) * 2;
    H[ui]     = packbf(s.x, s.y);
    H[ui + 1] = packbf(s.z, s.w);
  }
  v4f acc[16];
#pragma unroll
  for (int j = 0; j < 16; ++j) acc[j] = (v4f){0.f, 0.f, 0.f, 0.f};
  int arow = wv * 16 + lm;
  int asw = (arow & 7) << 3;         // ushort-index swizzle (8 bf16 = 16B)
  for (int kt = 0; kt < 4; ++kt) {
    __syncthreads();
#pragma unroll
    for (int r = 0; r < 8; ++r)
      async16(w2t + (size_t)(srow + r * 32) * 256 + kt * 64 + scol,
              &Bs2[(srow + r * 32) * 64 + scol]);
    __syncthreads();
#pragma unroll
    for (int kk = 0; kk < 64; kk += 32) {
      v8bf a = *(const v8bf*)&HsA[arow * 256 + ((kt * 64 + kk + quad * 8) ^ asw)];
#pragma unroll
      for (int j = 0; j < 16; ++j) {
        v8bf b = *(const v8bf*)&Bs2[(j * 16 + lm) * 64 + kk + quad * 8];
        acc[j] = __builtin_amdgcn_mfma_f32_16x16x32_bf16(a, b, acc[j], 0, 0, 0);
      }
    }
  }
#pragma unroll
  for (int j = 0; j < 16; ++j) {
    int nn = j * 16 + lm;
    float bb = b2[nn];
#pragma unroll
    for (int r = 0; r < 4; ++r) {
      int row = wv * 16 + quad * 4 + r;
      Hs[row * 257 + nn] = fmaxf(acc[j][r] + bb, 0.f);
    }
  }
  __syncthreads();
  for (int o = tid; o < 384; o += 256) {
    int hd = o >> 6, r = o & 63;
    int grow = r0 + r;
    float d = 0.f;
    if (hd < 2) {
      for (int k = 0; k < 256; ++k) d += Hs[r * 257 + k] * wcls[k * 2 + hd];
      d += bcls[hd];
      if (grow < NROI) out[grow * 2 + hd] = d;
    } else {
      int h4 = hd - 2;
      for (int k = 0; k < 256; ++k) d += Hs[r * 257 + k] * wreg[k * 4 + h4];
      d += breg[h4];
      if (grow < NROI) out[4000 + grow * 4 + h4] = d;
    }
  }
}

extern "C" void kernel_launch(void* const* d_in, const int* in_sizes, int n_in,
                              void* d_out, int out_size, void* d_ws, size_t ws_size,
                              hipStream_t stream) {
  const float* features = (const float*)d_in[0];
  const int* rois = (const int*)d_in[1];
  const float* w1 = (const float*)d_in[2];
  const float* b1 = (const float*)d_in[3];
  const float* w2 = (const float*)d_in[4];
  const float* b2 = (const float*)d_in[5];
  const float* wcls = (const float*)d_in[6];
  const float* bcls = (const float*)d_in[7];
  const float* wreg = (const float*)d_in[8];
  const float* breg = (const float*)d_in[9];
  char* ws = (char*)d_ws;
  ushort* ft  = (ushort*)(ws + 0);          // 57,802,752 B
  ushort* w1t = (ushort*)(ws + 57802752);   //  6,422,528 B
  ushort* w2t = (ushort*)(ws + 64225280);   //    131,072 B
  ushort* rf  = (ushort*)(ws + 64356352);   // 51,380,224 B (2048 rows; rows
                                            // 2000+ are GEMM padding)
  // perm lives in rf's padding rows (read by gemm1 as harmless tiny bf16)
  int*    perm = (int*)(ws + 64356352 + (size_t)NROI * KDIM * 2);
  float*  P   = (float*)(ws + 115736576);   // 14,680,064 B used
  float* out = (float*)d_out;

  hipLaunchKernelGGL(k_trprep, dim3(NTRB + 425), dim3(256), 0, stream,
                     features, (uint*)ft, w1, (uint*)w1t, w2, w2t, rois, perm);
  hipLaunchKernelGGL(k_pool, dim3(NROI * 7), dim3(64), 0, stream, rois, perm,
                     (const uint2*)ft, (uint2*)rf);
  hipLaunchKernelGGL(k_gemm1, dim3(32, 2, SPLITK), dim3(256), 0, stream, rf, w1t, P);
  hipLaunchKernelGGL(k_gemm2, dim3(32), dim3(256), 0, stream, P, b1, w2t, b2,
                     wcls, bcls, wreg, breg, out);
}